// Round 3
// baseline (159.617 us; speedup 1.0000x reference)
//
#include <hip/hip_runtime.h>

#define B_ 16
#define C_ 256
#define N_ 1024
#define NH 8
#define HD 32
#define KD 16
#define QKV_OUT_ 512
#define BN_EPS 1e-3f
// softmax scale * log2(e), pre-folded into the q-channel weights
#define SCALE2_ (0.25f * 1.44269504088896f)

typedef __attribute__((ext_vector_type(8))) short short8;
typedef __attribute__((ext_vector_type(16))) float float16;

__device__ inline unsigned short f2bf(float f) {
  unsigned int u = __float_as_uint(f);
  return (unsigned short)((u + 0x7FFF + ((u >> 16) & 1)) >> 16);  // RNE
}
__device__ inline float bf2f(unsigned short s) {
  return __uint_as_float(((unsigned int)s) << 16);
}
__device__ inline float16 zero16() {
  float16 z;
  #pragma unroll
  for (int i = 0; i < 16; ++i) z[i] = 0.f;
  return z;
}
__device__ inline unsigned int pack_bf16_trunc(float a, float b) {
  return __builtin_amdgcn_perm(__float_as_uint(b), __float_as_uint(a), 0x07060302u);
}
__device__ inline unsigned int pack_bf16_rne(float a, float b) {
  return (unsigned int)f2bf(a) | ((unsigned int)f2bf(b) << 16);
}
__device__ inline float fast_exp2(float x) {
#if __has_builtin(__builtin_amdgcn_exp2f)
  return __builtin_amdgcn_exp2f(x);
#else
  return exp2f(x);
#endif
}
// permlane32_swap: a' = {a.lo, b.lo}, b' = {a.hi, b.hi}
__device__ inline void pl32(unsigned int& a, unsigned int& b) {
#if __has_builtin(__builtin_amdgcn_permlane32_swap)
  typedef __attribute__((ext_vector_type(2))) int int2v;
  int2v r = __builtin_amdgcn_permlane32_swap((int)a, (int)b, false, false);
  a = (unsigned int)r[0];
  b = (unsigned int)r[1];
#else
  unsigned int ea = (unsigned int)__shfl_xor((int)a, 32, 64);
  unsigned int eb = (unsigned int)__shfl_xor((int)b, 32, 64);
  bool hi = (threadIdx.x & 32) != 0;
  unsigned int an = hi ? eb : a;
  unsigned int bn = hi ? b : ea;
  a = an; b = bn;
#endif
}
__device__ inline short8 lds_frag(const unsigned short* p) {
  union { uint2 u[2]; short8 s; } r;
  r.u[0] = *(const uint2*)p;
  r.u[1] = *(const uint2*)(p + 4);
  return r.s;
}
__device__ inline void lds_store16(unsigned short* p, uint4 v) {
  *(uint2*)p = make_uint2(v.x, v.y);
  *(uint2*)(p + 4) = make_uint2(v.z, v.w);
}

// ---------------------------------------------------------------------------
// Fold BN into conv weights (bf16) + bias.  q-channels (o%64 < 16) also get
// SCALE2_ folded so attention uses raw exp2 with no Q repack.
// NEW (round 3): extra blocks transpose x -> token-major bf16 xT[b][n][c]
// (RNE, bit-identical to the conversion previously done inside gemm_qkv's
// staging) so gemm_qkv can use clean 16B vector B-staging.  No extra launch.
// ---------------------------------------------------------------------------
__global__ __launch_bounds__(256) void fold_weights(
    const float* __restrict__ qkv_w, const float* __restrict__ qg,
    const float* __restrict__ qb, const float* __restrict__ qm,
    const float* __restrict__ qv,
    const float* __restrict__ proj_w, const float* __restrict__ pg,
    const float* __restrict__ pb, const float* __restrict__ pm,
    const float* __restrict__ pv,
    const float* __restrict__ x, unsigned short* __restrict__ xT,
    unsigned short* __restrict__ wq, float* __restrict__ biasq,
    unsigned short* __restrict__ wp, float* __restrict__ biasp)
{
  __shared__ float t[64][65];
  const int bx = blockIdx.x, c = threadIdx.x;
  if (bx < QKV_OUT_) {
    const int o = bx;
    float s = ((o & 63) < 16) ? SCALE2_ : 1.f;
    float inv = qg[o] * rsqrtf(qv[o] + BN_EPS) * s;
    wq[o * C_ + c] = f2bf(qkv_w[o * C_ + c] * inv);
    if (c == 0) biasq[o] = qb[o] * s - qm[o] * inv;
  } else if (bx < QKV_OUT_ + C_) {
    const int oo = bx - QKV_OUT_;
    float inv = pg[oo] * rsqrtf(pv[oo] + BN_EPS);
    wp[oo * C_ + c] = f2bf(proj_w[oo * C_ + c] * inv);
    if (c == 0) biasp[oo] = pb[oo] - pm[oo] * inv;
  } else {
    // x transpose tile: 64 tokens x 64 channels, coalesced both directions.
    const int tix = bx - (QKV_OUT_ + C_);
    const int b = tix >> 6, rem = tix & 63;
    const int n0 = (rem >> 2) * 64, c0 = (rem & 3) * 64;
    #pragma unroll
    for (int i = 0; i < 16; ++i) {
      int idx = i * 256 + c;
      int r = idx >> 6, col = idx & 63;          // r = channel row, col = token
      t[r][col] = x[((size_t)b * C_ + c0 + r) * N_ + n0 + col];
    }
    __syncthreads();
    #pragma unroll
    for (int i = 0; i < 16; ++i) {
      int idx = i * 256 + c;
      int rn = idx >> 6, cc = idx & 63;          // rn = token row, cc = channel
      xT[((size_t)b * N_ + n0 + rn) * C_ + c0 + cc] = f2bf(t[cc][rn]);
    }
  }
}

// ---------------------------------------------------------------------------
// qkv GEMM: tile 128(o) x 128(tok), BK=32, double-buffered LDS stride 44
// shorts (2-way bank aliasing = free), reg-prefetch, 1 barrier per K-step.
// Round 3: B-staging now reads pre-transposed bf16 xT with 2x16B vector
// loads per thread per K-step (was 16 scalar f32 loads + 16 RNE converts +
// 8 packs).  MFMA inputs bit-identical to before.
// Epilogue: q,k -> token-major qkT[b][h][token][32]; v -> planar bf16 vbuf.
// ---------------------------------------------------------------------------
__global__ __launch_bounds__(256) void gemm_qkv(
    const unsigned short* __restrict__ xT, const unsigned short* __restrict__ wq,
    const float* __restrict__ bias,
    unsigned short* __restrict__ qkT, unsigned short* __restrict__ vbuf)
{
  constexpr int STR = 44;
  __shared__ __align__(8) unsigned short wa[2][128 * STR];
  __shared__ __align__(8) unsigned short xb[2][128 * STR];
  const int tid = threadIdx.x;
  const int wave = tid >> 6, lane = tid & 63, l31 = lane & 31, lh = lane >> 5;
  const int wm = wave & 1, wn = wave >> 1;
  const int b = blockIdx.x >> 3, nloc = (blockIdx.x & 7) * 128;
  const int o0 = blockIdx.y * 128;

  // staging: 16B slots; thread covers rows ar, ar+64 of both A and B tiles
  const int ar = tid >> 2, aseg = (tid & 3) * 8;
  const unsigned short* xTb = xT + ((size_t)b * N_ + nloc) * C_;

  uint4 ga0, ga1, gb0, gb1;
  auto loadk = [&](int kc) {
    ga0 = *(const uint4*)(wq + (size_t)(o0 + ar) * C_ + kc * 32 + aseg);
    ga1 = *(const uint4*)(wq + (size_t)(o0 + ar + 64) * C_ + kc * 32 + aseg);
    gb0 = *(const uint4*)(xTb + (size_t)ar * C_ + kc * 32 + aseg);
    gb1 = *(const uint4*)(xTb + (size_t)(ar + 64) * C_ + kc * 32 + aseg);
  };
  auto storek = [&](int bufi) {
    lds_store16(&wa[bufi][ar * STR + aseg], ga0);
    lds_store16(&wa[bufi][(ar + 64) * STR + aseg], ga1);
    lds_store16(&xb[bufi][ar * STR + aseg], gb0);
    lds_store16(&xb[bufi][(ar + 64) * STR + aseg], gb1);
  };

  float16 acc[2][2];
  #pragma unroll
  for (int i = 0; i < 2; ++i)
    #pragma unroll
    for (int j = 0; j < 2; ++j) acc[i][j] = zero16();

  loadk(0);
  storek(0);
  __syncthreads();

  for (int kc = 0; kc < 8; ++kc) {
    const int buf = kc & 1;
    if (kc < 7) loadk(kc + 1);   // global loads land during MFMA

    #pragma unroll
    for (int ks = 0; ks < 2; ++ks) {
      const int ko = ks * 16 + lh * 8;
      short8 a0 = lds_frag(&wa[buf][(wm * 64 + l31) * STR + ko]);
      short8 a1 = lds_frag(&wa[buf][(wm * 64 + 32 + l31) * STR + ko]);
      short8 b0 = lds_frag(&xb[buf][(wn * 64 + l31) * STR + ko]);
      short8 b1 = lds_frag(&xb[buf][(wn * 64 + 32 + l31) * STR + ko]);
      acc[0][0] = __builtin_amdgcn_mfma_f32_32x32x16_bf16(a0, b0, acc[0][0], 0, 0, 0);
      acc[0][1] = __builtin_amdgcn_mfma_f32_32x32x16_bf16(a0, b1, acc[0][1], 0, 0, 0);
      acc[1][0] = __builtin_amdgcn_mfma_f32_32x32x16_bf16(a1, b0, acc[1][0], 0, 0, 0);
      acc[1][1] = __builtin_amdgcn_mfma_f32_32x32x16_bf16(a1, b1, acc[1][1], 0, 0, 0);
    }

    if (kc < 7) storek(buf ^ 1);
    __syncthreads();
  }

  const int hh = (o0 >> 6) + wm;  // o = o0 + wm*64 + am*32 + idx
  // am=0: q+k -> token-major qkT[b][hh][token][cc]
  #pragma unroll
  for (int bn = 0; bn < 2; ++bn) {
    int n = nloc + wn * 64 + bn * 32 + l31;
    unsigned short* row = qkT + (((size_t)b * NH + hh) * N_ + n) * 32;
    #pragma unroll
    for (int qd = 0; qd < 4; ++qd) {
      int cc0 = 8 * qd + 4 * lh;
      ushort4 rv;
      rv.x = f2bf(acc[0][bn][4 * qd + 0] + bias[hh * 64 + cc0 + 0]);
      rv.y = f2bf(acc[0][bn][4 * qd + 1] + bias[hh * 64 + cc0 + 1]);
      rv.z = f2bf(acc[0][bn][4 * qd + 2] + bias[hh * 64 + cc0 + 2]);
      rv.w = f2bf(acc[0][bn][4 * qd + 3] + bias[hh * 64 + cc0 + 3]);
      *(ushort4*)(row + cc0) = rv;
    }
  }
  // am=1: v -> planar bf16 vbuf[b][hh*32+d][n]
  #pragma unroll
  for (int r = 0; r < 16; ++r) {
    int d = (r & 3) + 8 * (r >> 2) + 4 * lh;
    float bo = bias[hh * 64 + 32 + d];
    unsigned short* vrow =
        vbuf + ((size_t)b * C_ + hh * 32 + d) * N_ + nloc + wn * 64 + l31;
    #pragma unroll
    for (int bn = 0; bn < 2; ++bn)
      vrow[bn * 32] = f2bf(acc[1][bn][r] + bo);
  }
}

// ---------------------------------------------------------------------------
// proj GEMM: 64(o) x 128(tok) tile, grid (128,4) = 512 blocks = 2/CU,
// LDS 34 KB.  Double-buffered stride-44 pipeline, 1 barrier per K-step.
// f32 planar out.
// ---------------------------------------------------------------------------
__global__ __launch_bounds__(256) void gemm_proj(
    const unsigned short* __restrict__ inT, const unsigned short* __restrict__ wp,
    const float* __restrict__ bias, float* __restrict__ outf)
{
  constexpr int STR = 44;
  __shared__ __align__(8) unsigned short wa[2][64 * STR];
  __shared__ __align__(8) unsigned short xb[2][128 * STR];
  const int tid = threadIdx.x;
  const int wave = tid >> 6, lane = tid & 63, l31 = lane & 31, lh = lane >> 5;
  const int wm = wave & 1, wn = wave >> 1;
  const int n0g = blockIdx.x * 128;
  const int o0 = blockIdx.y * 64;
  const int b = n0g >> 10, nloc = n0g & 1023;

  // A staging: 64 rows x 32 ch = 256 16B-slots (1/thread)
  const int ar = tid >> 2, aseg = (tid & 3) * 8;
  // B staging: 128 rows x 32 ch = 512 slots (2/thread: rows ar, ar+64)

  float16 acc[2];
  acc[0] = zero16(); acc[1] = zero16();

  uint4 ga, gb0, gb1;
  auto loadk = [&](int kc) {
    ga  = *(const uint4*)(wp + (size_t)(o0 + ar) * C_ + kc * 32 + aseg);
    gb0 = *(const uint4*)(inT + (size_t)(n0g + ar) * C_ + kc * 32 + aseg);
    gb1 = *(const uint4*)(inT + (size_t)(n0g + ar + 64) * C_ + kc * 32 + aseg);
  };
  auto storek = [&](int bufi) {
    lds_store16(&wa[bufi][ar * STR + aseg], ga);
    lds_store16(&xb[bufi][ar * STR + aseg], gb0);
    lds_store16(&xb[bufi][(ar + 64) * STR + aseg], gb1);
  };

  loadk(0);
  storek(0);
  __syncthreads();

  for (int kc = 0; kc < 8; ++kc) {
    const int buf = kc & 1;
    if (kc < 7) loadk(kc + 1);

    #pragma unroll
    for (int ks = 0; ks < 2; ++ks) {
      const int ko = ks * 16 + lh * 8;
      short8 a0 = lds_frag(&wa[buf][(wm * 32 + l31) * STR + ko]);
      short8 b0 = lds_frag(&xb[buf][(wn * 64 + l31) * STR + ko]);
      short8 b1 = lds_frag(&xb[buf][(wn * 64 + 32 + l31) * STR + ko]);
      acc[0] = __builtin_amdgcn_mfma_f32_32x32x16_bf16(a0, b0, acc[0], 0, 0, 0);
      acc[1] = __builtin_amdgcn_mfma_f32_32x32x16_bf16(a0, b1, acc[1], 0, 0, 0);
    }

    if (kc < 7) storek(buf ^ 1);
    __syncthreads();
  }

  #pragma unroll
  for (int r = 0; r < 16; ++r) {
    int o = o0 + wm * 32 + (r & 3) + 8 * (r >> 2) + 4 * lh;
    float bo = bias[o];
    float* orow = outf + ((size_t)b * C_ + o) * N_ + nloc + wn * 64 + l31;
    #pragma unroll
    for (int bn = 0; bn < 2; ++bn)
      orow[bn * 32] = acc[bn][r] + bo;
  }
}

// ---------------------------------------------------------------------------
// MFMA attention: 32 q/wave, grid (bh, qt) XCD-affine, LDS K/V double-
// buffered with reg-prefetch, conflict-free strides, permlane32_swap
// P-transpose, DUAL PV accumulators.
// Posenc (3x3 depthwise + BN) fused as a cooperative LDS pass:
//   stage:   v tile 32ch x 6rows(y-1..y+4) x 32px bf16 -> padded LDS rows
//   compute: 256 thr x (1ch,1row,16px): 12 LDS vec reads, 144 FMA -> pout
//   gather:  epilogue adds pout[d][y][x] via conflict-free scalar LDS reads
// ---------------------------------------------------------------------------
__global__ __launch_bounds__(256) void attn_mfma(
    const unsigned short* __restrict__ qkT, const unsigned short* __restrict__ vbuf,
    const float* __restrict__ pw, const float* __restrict__ peg,
    const float* __restrict__ peb, const float* __restrict__ pem,
    const float* __restrict__ pev, unsigned short* __restrict__ vattnT)
{
  __shared__ __align__(16) unsigned short k_lds[2][128 * 28];
  __shared__ __align__(16) unsigned short v_lds[2][32 * 140];

  const int tid = threadIdx.x;
  const int wave = tid >> 6, lane = tid & 63;
  const int l31 = lane & 31, lh = lane >> 5;
  const int b = blockIdx.x >> 3, h = blockIdx.x & 7;
  const int qbase = blockIdx.y * 128 + wave * 32;

  const unsigned short* qkb = qkT + ((size_t)b * NH + h) * N_ * 32;
  const unsigned short* vhead = vbuf + ((size_t)b * C_ + h * HD) * N_;

  const int skey = tid >> 1, shalf = tid & 1;
  const int svd = tid >> 3, svseg = tid & 7;

  // Q fragment: 64B-aligned row -> single 16B load (scale pre-folded)
  short8 qf = *(const short8*)(qkb + (size_t)(qbase + l31) * 32 + lh * 8);

  uint4 gk, gv0, gv1;
  auto loadc = [&](int kc) {
    gk  = *(const uint4*)(qkb + (size_t)(kc + skey) * 32 + 16 + shalf * 8);
    gv0 = *(const uint4*)(vhead + (size_t)svd * N_ + kc + svseg * 16);
    gv1 = *(const uint4*)(vhead + (size_t)svd * N_ + kc + svseg * 16 + 8);
  };
  auto storec = [&](int bufi) {
    lds_store16(&k_lds[bufi][skey * 28 + shalf * 8], gk);
    lds_store16(&v_lds[bufi][svd * 140 + svseg * 16], gv0);
    lds_store16(&v_lds[bufi][svd * 140 + svseg * 16 + 8], gv1);
  };

  loadc(0);
  storec(0);
  __syncthreads();

  float16 oaccE = zero16(), oaccO = zero16();
  float ls[4] = {0.f, 0.f, 0.f, 0.f};

  for (int c = 0; c < 8; ++c) {
    const int buf = c & 1;
    if (c < 7) loadc((c + 1) * 128);

    #pragma unroll
    for (int t = 0; t < 4; ++t) {
      const int key0 = t * 32;
      short8 kf = lds_frag(&k_lds[buf][(key0 + l31) * 28 + lh * 8]);
      float16 st = __builtin_amdgcn_mfma_f32_32x32x16_bf16(kf, qf, zero16(), 0, 0, 0);

      unsigned int u[8];
      #pragma unroll
      for (int q = 0; q < 8; ++q) {
        float pe = fast_exp2(st[2 * q]);
        float po = fast_exp2(st[2 * q + 1]);
        ls[q & 3] += pe + po;
        u[q] = pack_bf16_trunc(pe, po);
      }

      #pragma unroll
      for (int f = 0; f < 2; ++f) {
        short8 vf = lds_frag(&v_lds[buf][l31 * 140 + key0 + f * 16 + lh * 8]);
        const int q0 = f * 4;
        unsigned int a0 = u[q0], a2 = u[q0 + 2]; pl32(a0, a2);
        unsigned int a1 = u[q0 + 1], a3 = u[q0 + 3]; pl32(a1, a3);
        union { unsigned int w[4]; short8 s; } bf;
        bf.w[0] = a0; bf.w[1] = a1; bf.w[2] = a2; bf.w[3] = a3;
        if (f == 0)
          oaccE = __builtin_amdgcn_mfma_f32_32x32x16_bf16(vf, bf.s, oaccE, 0, 0, 0);
        else
          oaccO = __builtin_amdgcn_mfma_f32_32x32x16_bf16(vf, bf.s, oaccO, 0, 0, 0);
      }
    }

    if (c < 7) storec(buf ^ 1);
    __syncthreads();
  }
  // loop-end barrier passed: all waves done reading K/V LDS -> reuse pool.

  // ---- posenc stage A: v tile + BN-folded weights into LDS --------------
  const int R0 = blockIdx.y * 4;
  unsigned short* ptb = &v_lds[0][0] + 8;                    // rows 16B-aligned
  float* w12 = (float*)&k_lds[0][0];                         // [32][12] f32
  unsigned short* pout = (unsigned short*)((char*)&k_lds[0][0] + 32 * 12 * 4);

  if (tid == 0) lds_store16(&v_lds[0][0], make_uint4(0, 0, 0, 0));  // guard
  if (tid < 192) {
    const int d = tid / 6, ry = tid - d * 6;
    unsigned short* dst = ptb + d * 240 + ry * 40;
    const uint4 z = make_uint4(0, 0, 0, 0);
    lds_store16(dst + 32, z);                                // right pad
    const int yy = R0 - 1 + ry;
    if (yy >= 0 && yy < 32) {
      const unsigned short* src = vhead + (size_t)d * N_ + yy * 32;
      lds_store16(dst,      *(const uint4*)(src));
      lds_store16(dst + 8,  *(const uint4*)(src + 8));
      lds_store16(dst + 16, *(const uint4*)(src + 16));
      lds_store16(dst + 24, *(const uint4*)(src + 24));
    } else {
      lds_store16(dst, z); lds_store16(dst + 8, z);
      lds_store16(dst + 16, z); lds_store16(dst + 24, z);
    }
  }
  if (tid < 32) {
    const int cg = h * HD + tid;
    const float iv = peg[cg] * rsqrtf(pev[cg] + BN_EPS);
    float* wr = w12 + tid * 12;
    #pragma unroll
    for (int k = 0; k < 9; ++k) wr[k] = pw[cg * 9 + k] * iv;
    wr[9] = peb[cg] - pem[cg] * iv;
    wr[10] = 0.f; wr[11] = 0.f;
  }
  __syncthreads();

  // ---- posenc compute: thread = (d, row, 16-px strip) -------------------
  {
    const int d = tid >> 3, row = (tid >> 1) & 3, x0 = (tid & 1) * 16;
    const float* wr = w12 + d * 12;
    float wv[10];
    #pragma unroll
    for (int k = 0; k < 10; ++k) wv[k] = wr[k];
    float acc[16];
    #pragma unroll
    for (int j = 0; j < 16; ++j) acc[j] = wv[9];
    #pragma unroll
    for (int dy = 0; dy < 3; ++dy) {
      const unsigned short* base = ptb + d * 240 + (row + dy) * 40 + x0;
      float tv[18];
      tv[0] = bf2f(base[-1]);                      // x0-1 (guard/pad = 0)
      short8 s0 = lds_frag(base);
      short8 s1 = lds_frag(base + 8);
      #pragma unroll
      for (int j = 0; j < 8; ++j) {
        tv[1 + j] = bf2f((unsigned short)s0[j]);
        tv[9 + j] = bf2f((unsigned short)s1[j]);
      }
      tv[17] = bf2f(base[16]);                     // x0+16 (pad = 0 at x0=16)
      const float w0 = wv[dy * 3], w1 = wv[dy * 3 + 1], w2 = wv[dy * 3 + 2];
      #pragma unroll
      for (int j = 0; j < 16; ++j)
        acc[j] += w0 * tv[j] + w1 * tv[j + 1] + w2 * tv[j + 2];
    }
    unsigned short* po = pout + d * 128 + row * 32 + x0;
    unsigned int pk[8];
    #pragma unroll
    for (int q = 0; q < 8; ++q) pk[q] = pack_bf16_rne(acc[2 * q], acc[2 * q + 1]);
    lds_store16(po,     make_uint4(pk[0], pk[1], pk[2], pk[3]));
    lds_store16(po + 8, make_uint4(pk[4], pk[5], pk[6], pk[7]));
  }
  __syncthreads();

  // ---- softmax finish + gather posenc + token-major store ---------------
  float lsum = (ls[0] + ls[1]) + (ls[2] + ls[3]);
  lsum += __shfl_xor(lsum, 32, 64);
  const float linv = 1.f / lsum;

  const int token = qbase + l31;
  float val[16];
  #pragma unroll
  for (int r = 0; r < 16; ++r) {
    int d = (r & 3) + 8 * (r >> 2) + 4 * lh;
    val[r] = (oaccE[r] + oaccO[r]) * linv +
             bf2f(pout[d * 128 + wave * 32 + l31]);
  }
  unsigned int u[8];
  #pragma unroll
  for (int m = 0; m < 8; ++m) u[m] = pack_bf16_rne(val[2 * m], val[2 * m + 1]);
  pl32(u[0], u[4]); pl32(u[1], u[5]); pl32(u[2], u[6]); pl32(u[3], u[7]);
  unsigned short* row = vattnT + ((size_t)b * N_ + token) * C_ + h * HD + lh * 16;
  *(uint4*)(row)     = make_uint4(u[0], u[1], u[4], u[5]);
  *(uint4*)(row + 8) = make_uint4(u[2], u[3], u[6], u[7]);
}

// ---------------------------------------------------------------------------
extern "C" void kernel_launch(void* const* d_in, const int* in_sizes, int n_in,
                              void* d_out, int out_size, void* d_ws, size_t ws_size,
                              hipStream_t stream) {
  const float* x          = (const float*)d_in[0];
  const float* qkv_w      = (const float*)d_in[1];
  const float* qkv_gamma  = (const float*)d_in[2];
  const float* qkv_beta   = (const float*)d_in[3];
  const float* qkv_mean   = (const float*)d_in[4];
  const float* qkv_var    = (const float*)d_in[5];
  const float* pe_w       = (const float*)d_in[6];
  const float* pe_gamma   = (const float*)d_in[7];
  const float* pe_beta    = (const float*)d_in[8];
  const float* pe_mean    = (const float*)d_in[9];
  const float* pe_var     = (const float*)d_in[10];
  const float* proj_w     = (const float*)d_in[11];
  const float* proj_gamma = (const float*)d_in[12];
  const float* proj_beta  = (const float*)d_in[13];
  const float* proj_mean  = (const float*)d_in[14];
  const float* proj_var   = (const float*)d_in[15];
  float* out = (float*)d_out;

  char* ws = (char*)d_ws;
  unsigned short* qkT = (unsigned short*)ws;
  ws += (size_t)B_ * NH * N_ * 32 * sizeof(unsigned short);
  unsigned short* vbuf = (unsigned short*)ws;
  ws += (size_t)B_ * C_ * N_ * sizeof(unsigned short);
  unsigned short* vattnT = (unsigned short*)ws;
  ws += (size_t)B_ * N_ * C_ * sizeof(unsigned short);
  unsigned short* xT = (unsigned short*)ws;
  ws += (size_t)B_ * N_ * C_ * sizeof(unsigned short);
  unsigned short* wq = (unsigned short*)ws;
  ws += (size_t)QKV_OUT_ * C_ * sizeof(unsigned short);
  unsigned short* wp = (unsigned short*)ws;
  ws += (size_t)C_ * C_ * sizeof(unsigned short);
  float* biasq = (float*)ws; ws += QKV_OUT_ * sizeof(float);
  float* biasp = (float*)ws;

  // weight fold (768 blocks) + x transpose (1024 blocks), one launch
  fold_weights<<<dim3(QKV_OUT_ + C_ + B_ * 16 * 4), 256, 0, stream>>>(
      qkv_w, qkv_gamma, qkv_beta, qkv_mean, qkv_var,
      proj_w, proj_gamma, proj_beta, proj_mean, proj_var,
      x, xT, wq, biasq, wp, biasp);

  // qkv GEMM (vector-staged from xT): grid.x = (b, ntile), grid.y = otile
  gemm_qkv<<<dim3(128, 4), 256, 0, stream>>>(xT, wq, biasq, qkT, vbuf);

  // attention (posenc fused, cooperative LDS conv): grid.x = bh, grid.y = qt
  attn_mfma<<<dim3(128, 8), 256, 0, stream>>>(
      qkT, vbuf, pe_w, pe_gamma, pe_beta, pe_mean, pe_var, vattnT);

  // proj GEMM: grid (ntile, otile) = 512 blocks (2/CU)
  gemm_proj<<<dim3(128, 4), 256, 0, stream>>>(vattnT, wp, biasp, out);
}

// Round 4
// 146.560 us; speedup vs baseline: 1.0891x; 1.0891x over previous
//
#include <hip/hip_runtime.h>

#define B_ 16
#define C_ 256
#define N_ 1024
#define NH 8
#define HD 32
#define KD 16
#define QKV_OUT_ 512
#define BN_EPS 1e-3f
// softmax scale * log2(e), pre-folded into the q-channel weights
#define SCALE2_ (0.25f * 1.44269504088896f)

typedef __attribute__((ext_vector_type(8))) short short8;
typedef __attribute__((ext_vector_type(16))) float float16;

__device__ inline unsigned short f2bf(float f) {
  unsigned int u = __float_as_uint(f);
  return (unsigned short)((u + 0x7FFF + ((u >> 16) & 1)) >> 16);  // RNE
}
__device__ inline float bf2f(unsigned short s) {
  return __uint_as_float(((unsigned int)s) << 16);
}
__device__ inline float16 zero16() {
  float16 z;
  #pragma unroll
  for (int i = 0; i < 16; ++i) z[i] = 0.f;
  return z;
}
__device__ inline unsigned int pack_bf16_trunc(float a, float b) {
  return __builtin_amdgcn_perm(__float_as_uint(b), __float_as_uint(a), 0x07060302u);
}
__device__ inline unsigned int pack_bf16_rne(float a, float b) {
  return (unsigned int)f2bf(a) | ((unsigned int)f2bf(b) << 16);
}
__device__ inline float fast_exp2(float x) {
#if __has_builtin(__builtin_amdgcn_exp2f)
  return __builtin_amdgcn_exp2f(x);
#else
  return exp2f(x);
#endif
}
// permlane32_swap: a' = {a.lo, b.lo}, b' = {a.hi, b.hi}
__device__ inline void pl32(unsigned int& a, unsigned int& b) {
#if __has_builtin(__builtin_amdgcn_permlane32_swap)
  typedef __attribute__((ext_vector_type(2))) int int2v;
  int2v r = __builtin_amdgcn_permlane32_swap((int)a, (int)b, false, false);
  a = (unsigned int)r[0];
  b = (unsigned int)r[1];
#else
  unsigned int ea = (unsigned int)__shfl_xor((int)a, 32, 64);
  unsigned int eb = (unsigned int)__shfl_xor((int)b, 32, 64);
  bool hi = (threadIdx.x & 32) != 0;
  unsigned int an = hi ? eb : a;
  unsigned int bn = hi ? b : ea;
  a = an; b = bn;
#endif
}
__device__ inline short8 lds_frag(const unsigned short* p) {
  union { uint2 u[2]; short8 s; } r;
  r.u[0] = *(const uint2*)p;
  r.u[1] = *(const uint2*)(p + 4);
  return r.s;
}
__device__ inline void lds_store16(unsigned short* p, uint4 v) {
  *(uint2*)p = make_uint2(v.x, v.y);
  *(uint2*)(p + 4) = make_uint2(v.z, v.w);
}

// ---------------------------------------------------------------------------
// Fold BN into conv weights (bf16) + bias.  q-channels (o%64 < 16) also get
// SCALE2_ folded so attention uses raw exp2 with no Q repack.
// ---------------------------------------------------------------------------
__global__ __launch_bounds__(256) void fold_weights(
    const float* __restrict__ qkv_w, const float* __restrict__ qg,
    const float* __restrict__ qb, const float* __restrict__ qm,
    const float* __restrict__ qv,
    const float* __restrict__ proj_w, const float* __restrict__ pg,
    const float* __restrict__ pb, const float* __restrict__ pm,
    const float* __restrict__ pv,
    unsigned short* __restrict__ wq, float* __restrict__ biasq,
    unsigned short* __restrict__ wp, float* __restrict__ biasp)
{
  const int o = blockIdx.x, c = threadIdx.x;
  if (o < QKV_OUT_) {
    float s = ((o & 63) < 16) ? SCALE2_ : 1.f;
    float inv = qg[o] * rsqrtf(qv[o] + BN_EPS) * s;
    wq[o * C_ + c] = f2bf(qkv_w[o * C_ + c] * inv);
    if (c == 0) biasq[o] = qb[o] * s - qm[o] * inv;
  } else {
    int oo = o - QKV_OUT_;
    float inv = pg[oo] * rsqrtf(pv[oo] + BN_EPS);
    wp[oo * C_ + c] = f2bf(proj_w[oo * C_ + c] * inv);
    if (c == 0) biasp[oo] = pb[oo] - pm[oo] * inv;
  }
}

// ---------------------------------------------------------------------------
// qkv GEMM (round-2 version restored): fused x transpose, tile 128(o) x
// 128(tok), BK=32, double-buffered LDS stride 44 shorts, reg-prefetch,
// 1 barrier per K-step.
// Epilogue: q,k -> token-major qkT[b][h][token][32]; v -> planar bf16 vbuf.
// ---------------------------------------------------------------------------
__global__ __launch_bounds__(256) void gemm_qkv(
    const float* __restrict__ x, const unsigned short* __restrict__ wq,
    const float* __restrict__ bias,
    unsigned short* __restrict__ qkT, unsigned short* __restrict__ vbuf)
{
  constexpr int STR = 44;
  __shared__ __align__(8) unsigned short wa[2][128 * STR];
  __shared__ __align__(8) unsigned short xb[2][128 * STR];
  const int tid = threadIdx.x;
  const int wave = tid >> 6, lane = tid & 63, l31 = lane & 31, lh = lane >> 5;
  const int wm = wave & 1, wn = wave >> 1;
  const int b = blockIdx.x >> 3, nloc = (blockIdx.x & 7) * 128;
  const int o0 = blockIdx.y * 128;

  // A staging: 512 slots of 16B; thread covers slots tid, tid+256
  const int r0 = tid >> 2, oc0 = (tid & 3) * 8;
  const int r1 = r0 + 64;
  // B staging: token tok, channel half chalf (16 ch), 16 scalar f32 loads
  const int tok = tid & 127, chalf = (tid >> 7) * 16;
  const float* xbase = x + (size_t)b * C_ * N_ + nloc + tok;

  uint4 ga0, ga1;
  float nb[16];

  auto loadk = [&](int kc) {
    ga0 = *(const uint4*)(wq + (size_t)(o0 + r0) * C_ + kc * 32 + oc0);
    ga1 = *(const uint4*)(wq + (size_t)(o0 + r1) * C_ + kc * 32 + oc0);
    #pragma unroll
    for (int j = 0; j < 16; ++j)
      nb[j] = xbase[(size_t)(kc * 32 + chalf + j) * N_];
  };
  auto storek = [&](int bufi) {
    lds_store16(&wa[bufi][r0 * STR + oc0], ga0);
    lds_store16(&wa[bufi][r1 * STR + oc0], ga1);
    unsigned int pk[8];
    #pragma unroll
    for (int q = 0; q < 8; ++q) pk[q] = pack_bf16_rne(nb[2 * q], nb[2 * q + 1]);
    lds_store16(&xb[bufi][tok * STR + chalf], make_uint4(pk[0], pk[1], pk[2], pk[3]));
    lds_store16(&xb[bufi][tok * STR + chalf + 8], make_uint4(pk[4], pk[5], pk[6], pk[7]));
  };

  float16 acc[2][2];
  #pragma unroll
  for (int i = 0; i < 2; ++i)
    #pragma unroll
    for (int j = 0; j < 2; ++j) acc[i][j] = zero16();

  loadk(0);
  storek(0);
  __syncthreads();

  for (int kc = 0; kc < 8; ++kc) {
    const int buf = kc & 1;
    if (kc < 7) loadk(kc + 1);   // global loads land during MFMA

    #pragma unroll
    for (int ks = 0; ks < 2; ++ks) {
      const int ko = ks * 16 + lh * 8;
      short8 a0 = lds_frag(&wa[buf][(wm * 64 + l31) * STR + ko]);
      short8 a1 = lds_frag(&wa[buf][(wm * 64 + 32 + l31) * STR + ko]);
      short8 b0 = lds_frag(&xb[buf][(wn * 64 + l31) * STR + ko]);
      short8 b1 = lds_frag(&xb[buf][(wn * 64 + 32 + l31) * STR + ko]);
      acc[0][0] = __builtin_amdgcn_mfma_f32_32x32x16_bf16(a0, b0, acc[0][0], 0, 0, 0);
      acc[0][1] = __builtin_amdgcn_mfma_f32_32x32x16_bf16(a0, b1, acc[0][1], 0, 0, 0);
      acc[1][0] = __builtin_amdgcn_mfma_f32_32x32x16_bf16(a1, b0, acc[1][0], 0, 0, 0);
      acc[1][1] = __builtin_amdgcn_mfma_f32_32x32x16_bf16(a1, b1, acc[1][1], 0, 0, 0);
    }

    if (kc < 7) storek(buf ^ 1);
    __syncthreads();
  }

  const int hh = (o0 >> 6) + wm;  // o = o0 + wm*64 + am*32 + idx
  // am=0: q+k -> token-major qkT[b][hh][token][cc]
  #pragma unroll
  for (int bn = 0; bn < 2; ++bn) {
    int n = nloc + wn * 64 + bn * 32 + l31;
    unsigned short* row = qkT + (((size_t)b * NH + hh) * N_ + n) * 32;
    #pragma unroll
    for (int qd = 0; qd < 4; ++qd) {
      int cc0 = 8 * qd + 4 * lh;
      ushort4 rv;
      rv.x = f2bf(acc[0][bn][4 * qd + 0] + bias[hh * 64 + cc0 + 0]);
      rv.y = f2bf(acc[0][bn][4 * qd + 1] + bias[hh * 64 + cc0 + 1]);
      rv.z = f2bf(acc[0][bn][4 * qd + 2] + bias[hh * 64 + cc0 + 2]);
      rv.w = f2bf(acc[0][bn][4 * qd + 3] + bias[hh * 64 + cc0 + 3]);
      *(ushort4*)(row + cc0) = rv;
    }
  }
  // am=1: v -> planar bf16 vbuf[b][hh*32+d][n]
  #pragma unroll
  for (int r = 0; r < 16; ++r) {
    int d = (r & 3) + 8 * (r >> 2) + 4 * lh;
    float bo = bias[hh * 64 + 32 + d];
    unsigned short* vrow =
        vbuf + ((size_t)b * C_ + hh * 32 + d) * N_ + nloc + wn * 64 + l31;
    #pragma unroll
    for (int bn = 0; bn < 2; ++bn)
      vrow[bn * 32] = f2bf(acc[1][bn][r] + bo);
  }
}

// ---------------------------------------------------------------------------
// proj GEMM: 64(o) x 128(tok) tile, grid (128,4) = 512 blocks = 2/CU,
// LDS 34 KB.  Double-buffered stride-44 pipeline, 1 barrier per K-step.
// f32 planar out.
// ---------------------------------------------------------------------------
__global__ __launch_bounds__(256) void gemm_proj(
    const unsigned short* __restrict__ inT, const unsigned short* __restrict__ wp,
    const float* __restrict__ bias, float* __restrict__ outf)
{
  constexpr int STR = 44;
  __shared__ __align__(8) unsigned short wa[2][64 * STR];
  __shared__ __align__(8) unsigned short xb[2][128 * STR];
  const int tid = threadIdx.x;
  const int wave = tid >> 6, lane = tid & 63, l31 = lane & 31, lh = lane >> 5;
  const int wm = wave & 1, wn = wave >> 1;
  const int n0g = blockIdx.x * 128;
  const int o0 = blockIdx.y * 64;
  const int b = n0g >> 10, nloc = n0g & 1023;

  // A staging: 64 rows x 32 ch = 256 16B-slots (1/thread)
  const int ar = tid >> 2, aseg = (tid & 3) * 8;
  // B staging: 128 rows x 32 ch = 512 slots (2/thread: rows ar, ar+64)

  float16 acc[2];
  acc[0] = zero16(); acc[1] = zero16();

  uint4 ga, gb0, gb1;
  auto loadk = [&](int kc) {
    ga  = *(const uint4*)(wp + (size_t)(o0 + ar) * C_ + kc * 32 + aseg);
    gb0 = *(const uint4*)(inT + (size_t)(n0g + ar) * C_ + kc * 32 + aseg);
    gb1 = *(const uint4*)(inT + (size_t)(n0g + ar + 64) * C_ + kc * 32 + aseg);
  };
  auto storek = [&](int bufi) {
    lds_store16(&wa[bufi][ar * STR + aseg], ga);
    lds_store16(&xb[bufi][ar * STR + aseg], gb0);
    lds_store16(&xb[bufi][(ar + 64) * STR + aseg], gb1);
  };

  loadk(0);
  storek(0);
  __syncthreads();

  for (int kc = 0; kc < 8; ++kc) {
    const int buf = kc & 1;
    if (kc < 7) loadk(kc + 1);

    #pragma unroll
    for (int ks = 0; ks < 2; ++ks) {
      const int ko = ks * 16 + lh * 8;
      short8 a0 = lds_frag(&wa[buf][(wm * 32 + l31) * STR + ko]);
      short8 b0 = lds_frag(&xb[buf][(wn * 64 + l31) * STR + ko]);
      short8 b1 = lds_frag(&xb[buf][(wn * 64 + 32 + l31) * STR + ko]);
      acc[0] = __builtin_amdgcn_mfma_f32_32x32x16_bf16(a0, b0, acc[0], 0, 0, 0);
      acc[1] = __builtin_amdgcn_mfma_f32_32x32x16_bf16(a0, b1, acc[1], 0, 0, 0);
    }

    if (kc < 7) storek(buf ^ 1);
    __syncthreads();
  }

  #pragma unroll
  for (int r = 0; r < 16; ++r) {
    int o = o0 + wm * 32 + (r & 3) + 8 * (r >> 2) + 4 * lh;
    float bo = bias[o];
    float* orow = outf + ((size_t)b * C_ + o) * N_ + nloc + wn * 64 + l31;
    #pragma unroll
    for (int bn = 0; bn < 2; ++bn)
      orow[bn * 32] = acc[bn][r] + bo;
  }
}

// ---------------------------------------------------------------------------
// MFMA attention, round 4: 64 q/wave (TWO 32-row groups per wave) for 2x
// ILP on the latency-bound QK->exp->PV chain (MfmaUtil was 9%, VALUBusy 42%,
// HBM 5% -- every pipe idle waiting on dependencies).  kf/vf LDS reads are
// SHARED between groups; 2 independent QK MFMAs + 2 exp chains + 4 PV MFMAs
// interleave.  Blocks halve (512): K/V global traffic and barrier count
// halve too.  s_setprio(1) around MFMA clusters.
// Posenc fused as cooperative LDS pass over 8 image rows (10-row staged
// tile, zero-padded), then gathered in the epilogue.
// ---------------------------------------------------------------------------
__global__ __launch_bounds__(256, 2) void attn_mfma(
    const unsigned short* __restrict__ qkT, const unsigned short* __restrict__ vbuf,
    const float* __restrict__ pw, const float* __restrict__ peg,
    const float* __restrict__ peb, const float* __restrict__ pem,
    const float* __restrict__ pev, unsigned short* __restrict__ vattnT)
{
  // flat pool: main loop uses kl[2][128*28] (7168) + vl[2][32*140] (8960).
  // posenc phase reuses it: w12 [32][12] f32 (768 sh) | guard 8 sh |
  // ptb [32][10][40] (12800 sh) | pout [32][8][32] (8192 sh) = 21776 sh.
  __shared__ __align__(16) unsigned short smem[21792];
  unsigned short* kl = smem;            // [2][3584]
  unsigned short* vl = smem + 7168;     // [2][4480]

  const int tid = threadIdx.x;
  const int wave = tid >> 6, lane = tid & 63;
  const int l31 = lane & 31, lh = lane >> 5;
  const int b = blockIdx.x >> 3, h = blockIdx.x & 7;
  const int qbase = blockIdx.y * 256 + wave * 64;

  const unsigned short* qkb = qkT + ((size_t)b * NH + h) * N_ * 32;
  const unsigned short* vhead = vbuf + ((size_t)b * C_ + h * HD) * N_;

  const int skey = tid >> 1, shalf = tid & 1;
  const int svd = tid >> 3, svseg = tid & 7;

  // Q fragments for both 32-row groups (scale pre-folded in weights)
  short8 qfE = *(const short8*)(qkb + (size_t)(qbase + l31) * 32 + lh * 8);
  short8 qfF = *(const short8*)(qkb + (size_t)(qbase + 32 + l31) * 32 + lh * 8);

  uint4 gk, gv0, gv1;
  auto loadc = [&](int kc) {
    gk  = *(const uint4*)(qkb + (size_t)(kc + skey) * 32 + 16 + shalf * 8);
    gv0 = *(const uint4*)(vhead + (size_t)svd * N_ + kc + svseg * 16);
    gv1 = *(const uint4*)(vhead + (size_t)svd * N_ + kc + svseg * 16 + 8);
  };
  auto storec = [&](int bufi) {
    lds_store16(&kl[bufi * 3584 + skey * 28 + shalf * 8], gk);
    lds_store16(&vl[bufi * 4480 + svd * 140 + svseg * 16], gv0);
    lds_store16(&vl[bufi * 4480 + svd * 140 + svseg * 16 + 8], gv1);
  };

  loadc(0);
  storec(0);
  __syncthreads();

  float16 o0E = zero16(), o0O = zero16(), o1E = zero16(), o1O = zero16();
  float lsE[4] = {0.f, 0.f, 0.f, 0.f};
  float lsF[4] = {0.f, 0.f, 0.f, 0.f};

  for (int c = 0; c < 8; ++c) {
    const int buf = c & 1;
    if (c < 7) loadc((c + 1) * 128);

    #pragma unroll
    for (int t = 0; t < 4; ++t) {
      const int key0 = t * 32;
      // shared operands: one K fragment + both V fragments, hoisted so LDS
      // latency overlaps the MFMA/exp work
      short8 kf  = lds_frag(&kl[buf * 3584 + (key0 + l31) * 28 + lh * 8]);
      short8 vf0 = lds_frag(&vl[buf * 4480 + l31 * 140 + key0 + lh * 8]);
      short8 vf1 = lds_frag(&vl[buf * 4480 + l31 * 140 + key0 + 16 + lh * 8]);

      __builtin_amdgcn_s_setprio(1);
      float16 stE = __builtin_amdgcn_mfma_f32_32x32x16_bf16(kf, qfE, zero16(), 0, 0, 0);
      float16 stF = __builtin_amdgcn_mfma_f32_32x32x16_bf16(kf, qfF, zero16(), 0, 0, 0);
      __builtin_amdgcn_s_setprio(0);

      unsigned int uE[8], uF[8];
      #pragma unroll
      for (int q = 0; q < 8; ++q) {
        float pe = fast_exp2(stE[2 * q]);
        float po = fast_exp2(stE[2 * q + 1]);
        lsE[q & 3] += pe + po;
        uE[q] = pack_bf16_trunc(pe, po);
      }
      #pragma unroll
      for (int q = 0; q < 8; ++q) {
        float pe = fast_exp2(stF[2 * q]);
        float po = fast_exp2(stF[2 * q + 1]);
        lsF[q & 3] += pe + po;
        uF[q] = pack_bf16_trunc(pe, po);
      }

      union { unsigned int w[4]; short8 s; } bE0, bE1, bF0, bF1;
      {
        unsigned int a0 = uE[0], a2 = uE[2]; pl32(a0, a2);
        unsigned int a1 = uE[1], a3 = uE[3]; pl32(a1, a3);
        bE0.w[0] = a0; bE0.w[1] = a1; bE0.w[2] = a2; bE0.w[3] = a3;
        unsigned int c0 = uE[4], c2 = uE[6]; pl32(c0, c2);
        unsigned int c1 = uE[5], c3 = uE[7]; pl32(c1, c3);
        bE1.w[0] = c0; bE1.w[1] = c1; bE1.w[2] = c2; bE1.w[3] = c3;
      }
      {
        unsigned int a0 = uF[0], a2 = uF[2]; pl32(a0, a2);
        unsigned int a1 = uF[1], a3 = uF[3]; pl32(a1, a3);
        bF0.w[0] = a0; bF0.w[1] = a1; bF0.w[2] = a2; bF0.w[3] = a3;
        unsigned int c0 = uF[4], c2 = uF[6]; pl32(c0, c2);
        unsigned int c1 = uF[5], c3 = uF[7]; pl32(c1, c3);
        bF1.w[0] = c0; bF1.w[1] = c1; bF1.w[2] = c2; bF1.w[3] = c3;
      }

      __builtin_amdgcn_s_setprio(1);
      o0E = __builtin_amdgcn_mfma_f32_32x32x16_bf16(vf0, bE0.s, o0E, 0, 0, 0);
      o1E = __builtin_amdgcn_mfma_f32_32x32x16_bf16(vf0, bF0.s, o1E, 0, 0, 0);
      o0O = __builtin_amdgcn_mfma_f32_32x32x16_bf16(vf1, bE1.s, o0O, 0, 0, 0);
      o1O = __builtin_amdgcn_mfma_f32_32x32x16_bf16(vf1, bF1.s, o1O, 0, 0, 0);
      __builtin_amdgcn_s_setprio(0);
    }

    if (c < 7) storec(buf ^ 1);
    __syncthreads();
  }
  // loop-end barrier passed: all waves done with K/V LDS -> reuse pool.

  // ---- posenc stage A: 10-row v tile + BN-folded weights into LDS -------
  const int R0 = blockIdx.y * 8;
  float* w12 = (float*)smem;                 // [32][12] f32
  unsigned short* ptb = smem + 776;          // guard at [768..775]
  unsigned short* pout = smem + 13576;       // [32][8][32]

  if (tid == 0) lds_store16(&smem[768], make_uint4(0, 0, 0, 0));  // guard
  #pragma unroll
  for (int it = 0; it < 2; ++it) {
    const int i = tid + it * 256;
    if (i < 320) {
      const int d = i / 10, ry = i - d * 10;
      unsigned short* dst = ptb + d * 400 + ry * 40;
      const uint4 z = make_uint4(0, 0, 0, 0);
      lds_store16(dst + 32, z);                                // right pad
      const int yy = R0 - 1 + ry;
      if (yy >= 0 && yy < 32) {
        const unsigned short* src = vhead + (size_t)d * N_ + yy * 32;
        lds_store16(dst,      *(const uint4*)(src));
        lds_store16(dst + 8,  *(const uint4*)(src + 8));
        lds_store16(dst + 16, *(const uint4*)(src + 16));
        lds_store16(dst + 24, *(const uint4*)(src + 24));
      } else {
        lds_store16(dst, z); lds_store16(dst + 8, z);
        lds_store16(dst + 16, z); lds_store16(dst + 24, z);
      }
    }
  }
  if (tid < 32) {
    const int cg = h * HD + tid;
    const float iv = peg[cg] * rsqrtf(pev[cg] + BN_EPS);
    float* wr = w12 + tid * 12;
    #pragma unroll
    for (int k = 0; k < 9; ++k) wr[k] = pw[cg * 9 + k] * iv;
    wr[9] = peb[cg] - pem[cg] * iv;
    wr[10] = 0.f; wr[11] = 0.f;
  }
  __syncthreads();

  // ---- posenc compute: 512 items = (d, row(8), 16-px strip), 2/thread ---
  #pragma unroll
  for (int it = 0; it < 2; ++it) {
    const int item = tid + it * 256;
    const int d = item >> 4, row = (item >> 1) & 7, x0 = (item & 1) * 16;
    const float* wr = w12 + d * 12;
    float wv[10];
    #pragma unroll
    for (int k = 0; k < 10; ++k) wv[k] = wr[k];
    float acc[16];
    #pragma unroll
    for (int j = 0; j < 16; ++j) acc[j] = wv[9];
    #pragma unroll
    for (int dy = 0; dy < 3; ++dy) {
      const unsigned short* base = ptb + d * 400 + (row + dy) * 40 + x0;
      float tv[18];
      tv[0] = bf2f(base[-1]);                      // pad/guard = 0
      short8 s0 = lds_frag(base);
      short8 s1 = lds_frag(base + 8);
      #pragma unroll
      for (int j = 0; j < 8; ++j) {
        tv[1 + j] = bf2f((unsigned short)s0[j]);
        tv[9 + j] = bf2f((unsigned short)s1[j]);
      }
      tv[17] = bf2f(base[16]);                     // pad = 0 at x0=16
      const float w0 = wv[dy * 3], w1 = wv[dy * 3 + 1], w2 = wv[dy * 3 + 2];
      #pragma unroll
      for (int j = 0; j < 16; ++j)
        acc[j] += w0 * tv[j] + w1 * tv[j + 1] + w2 * tv[j + 2];
    }
    unsigned short* po = pout + d * 256 + row * 32 + x0;
    unsigned int pk[8];
    #pragma unroll
    for (int q = 0; q < 8; ++q) pk[q] = pack_bf16_rne(acc[2 * q], acc[2 * q + 1]);
    lds_store16(po,     make_uint4(pk[0], pk[1], pk[2], pk[3]));
    lds_store16(po + 8, make_uint4(pk[4], pk[5], pk[6], pk[7]));
  }
  __syncthreads();

  // ---- softmax finish + gather posenc + token-major store (2 groups) ----
  float lsumE = (lsE[0] + lsE[1]) + (lsE[2] + lsE[3]);
  lsumE += __shfl_xor(lsumE, 32, 64);
  const float linvE = 1.f / lsumE;
  float lsumF = (lsF[0] + lsF[1]) + (lsF[2] + lsF[3]);
  lsumF += __shfl_xor(lsumF, 32, 64);
  const float linvF = 1.f / lsumF;

  auto emit = [&](const float16& aE, const float16& aO, float linv, int g) {
    const int token = qbase + g * 32 + l31;
    const int yl = wave * 2 + g;                 // local image row in pout
    float val[16];
    #pragma unroll
    for (int r = 0; r < 16; ++r) {
      int d = (r & 3) + 8 * (r >> 2) + 4 * lh;
      val[r] = (aE[r] + aO[r]) * linv + bf2f(pout[d * 256 + yl * 32 + l31]);
    }
    unsigned int u[8];
    #pragma unroll
    for (int m = 0; m < 8; ++m) u[m] = pack_bf16_rne(val[2 * m], val[2 * m + 1]);
    pl32(u[0], u[4]); pl32(u[1], u[5]); pl32(u[2], u[6]); pl32(u[3], u[7]);
    unsigned short* row = vattnT + ((size_t)b * N_ + token) * C_ + h * HD + lh * 16;
    *(uint4*)(row)     = make_uint4(u[0], u[1], u[4], u[5]);
    *(uint4*)(row + 8) = make_uint4(u[2], u[3], u[6], u[7]);
  };
  emit(o0E, o0O, linvE, 0);
  emit(o1E, o1O, linvF, 1);
}

// ---------------------------------------------------------------------------
extern "C" void kernel_launch(void* const* d_in, const int* in_sizes, int n_in,
                              void* d_out, int out_size, void* d_ws, size_t ws_size,
                              hipStream_t stream) {
  const float* x          = (const float*)d_in[0];
  const float* qkv_w      = (const float*)d_in[1];
  const float* qkv_gamma  = (const float*)d_in[2];
  const float* qkv_beta   = (const float*)d_in[3];
  const float* qkv_mean   = (const float*)d_in[4];
  const float* qkv_var    = (const float*)d_in[5];
  const float* pe_w       = (const float*)d_in[6];
  const float* pe_gamma   = (const float*)d_in[7];
  const float* pe_beta    = (const float*)d_in[8];
  const float* pe_mean    = (const float*)d_in[9];
  const float* pe_var     = (const float*)d_in[10];
  const float* proj_w     = (const float*)d_in[11];
  const float* proj_gamma = (const float*)d_in[12];
  const float* proj_beta  = (const float*)d_in[13];
  const float* proj_mean  = (const float*)d_in[14];
  const float* proj_var   = (const float*)d_in[15];
  float* out = (float*)d_out;

  char* ws = (char*)d_ws;
  unsigned short* qkT = (unsigned short*)ws;
  ws += (size_t)B_ * NH * N_ * 32 * sizeof(unsigned short);
  unsigned short* vbuf = (unsigned short*)ws;
  ws += (size_t)B_ * C_ * N_ * sizeof(unsigned short);
  unsigned short* vattnT = (unsigned short*)ws;
  ws += (size_t)B_ * N_ * C_ * sizeof(unsigned short);
  unsigned short* wq = (unsigned short*)ws;
  ws += (size_t)QKV_OUT_ * C_ * sizeof(unsigned short);
  unsigned short* wp = (unsigned short*)ws;
  ws += (size_t)C_ * C_ * sizeof(unsigned short);
  float* biasq = (float*)ws; ws += QKV_OUT_ * sizeof(float);
  float* biasp = (float*)ws;

  fold_weights<<<dim3(QKV_OUT_ + C_), 256, 0, stream>>>(
      qkv_w, qkv_gamma, qkv_beta, qkv_mean, qkv_var,
      proj_w, proj_gamma, proj_beta, proj_mean, proj_var,
      wq, biasq, wp, biasp);

  // qkv GEMM (fused transpose): grid.x = (b, ntile), grid.y = otile
  gemm_qkv<<<dim3(128, 4), 256, 0, stream>>>(x, wq, biasq, qkT, vbuf);

  // attention (64 q/wave, posenc fused): grid.x = bh, grid.y = q-tile(256)
  attn_mfma<<<dim3(128, 4), 256, 0, stream>>>(
      qkT, vbuf, pe_w, pe_gamma, pe_beta, pe_mean, pe_var, vattnT);

  // proj GEMM: grid (ntile, otile) = 512 blocks (2/CU)
  gemm_proj<<<dim3(128, 4), 256, 0, stream>>>(vattnT, wp, biasp, out);
}

// Round 5
// 146.318 us; speedup vs baseline: 1.0909x; 1.0017x over previous
//
#include <hip/hip_runtime.h>

#define B_ 16
#define C_ 256
#define N_ 1024
#define NH 8
#define HD 32
#define KD 16
#define QKV_OUT_ 512
#define BN_EPS 1e-3f
// softmax scale * log2(e), pre-folded into the q-channel weights
#define SCALE2_ (0.25f * 1.44269504088896f)

typedef __attribute__((ext_vector_type(8))) short short8;
typedef __attribute__((ext_vector_type(16))) float float16;

__device__ inline unsigned short f2bf(float f) {
  unsigned int u = __float_as_uint(f);
  return (unsigned short)((u + 0x7FFF + ((u >> 16) & 1)) >> 16);  // RNE
}
__device__ inline float bf2f(unsigned short s) {
  return __uint_as_float(((unsigned int)s) << 16);
}
__device__ inline float16 zero16() {
  float16 z;
  #pragma unroll
  for (int i = 0; i < 16; ++i) z[i] = 0.f;
  return z;
}
__device__ inline unsigned int pack_bf16_trunc(float a, float b) {
  return __builtin_amdgcn_perm(__float_as_uint(b), __float_as_uint(a), 0x07060302u);
}
__device__ inline unsigned int pack_bf16_rne(float a, float b) {
  return (unsigned int)f2bf(a) | ((unsigned int)f2bf(b) << 16);
}
// single-instruction packed f32x2 -> bf16x2 (RNE in HW; no builtin on gfx950)
__device__ inline unsigned int cvt_pk_bf16(float lo, float hi) {
  unsigned int d;
  asm("v_cvt_pk_bf16_f32 %0, %1, %2" : "=v"(d) : "v"(lo), "v"(hi));
  return d;
}
__device__ inline float fast_exp2(float x) {
#if __has_builtin(__builtin_amdgcn_exp2f)
  return __builtin_amdgcn_exp2f(x);
#else
  return exp2f(x);
#endif
}
// permlane32_swap: a' = {a.lo, b.lo}, b' = {a.hi, b.hi}
__device__ inline void pl32(unsigned int& a, unsigned int& b) {
#if __has_builtin(__builtin_amdgcn_permlane32_swap)
  typedef __attribute__((ext_vector_type(2))) int int2v;
  int2v r = __builtin_amdgcn_permlane32_swap((int)a, (int)b, false, false);
  a = (unsigned int)r[0];
  b = (unsigned int)r[1];
#else
  unsigned int ea = (unsigned int)__shfl_xor((int)a, 32, 64);
  unsigned int eb = (unsigned int)__shfl_xor((int)b, 32, 64);
  bool hi = (threadIdx.x & 32) != 0;
  unsigned int an = hi ? eb : a;
  unsigned int bn = hi ? b : ea;
  a = an; b = bn;
#endif
}
__device__ inline short8 lds_frag(const unsigned short* p) {
  union { uint2 u[2]; short8 s; } r;
  r.u[0] = *(const uint2*)p;
  r.u[1] = *(const uint2*)(p + 4);
  return r.s;
}
__device__ inline void lds_store16(unsigned short* p, uint4 v) {
  *(uint2*)p = make_uint2(v.x, v.y);
  *(uint2*)(p + 4) = make_uint2(v.z, v.w);
}

// ---------------------------------------------------------------------------
// Fold BN into conv weights (bf16) + bias.  q-channels (o%64 < 16) also get
// SCALE2_ folded so attention uses raw exp2 with no Q repack.
// ---------------------------------------------------------------------------
__global__ __launch_bounds__(256) void fold_weights(
    const float* __restrict__ qkv_w, const float* __restrict__ qg,
    const float* __restrict__ qb, const float* __restrict__ qm,
    const float* __restrict__ qv,
    const float* __restrict__ proj_w, const float* __restrict__ pg,
    const float* __restrict__ pb, const float* __restrict__ pm,
    const float* __restrict__ pv,
    unsigned short* __restrict__ wq, float* __restrict__ biasq,
    unsigned short* __restrict__ wp, float* __restrict__ biasp)
{
  const int o = blockIdx.x, c = threadIdx.x;
  if (o < QKV_OUT_) {
    float s = ((o & 63) < 16) ? SCALE2_ : 1.f;
    float inv = qg[o] * rsqrtf(qv[o] + BN_EPS) * s;
    wq[o * C_ + c] = f2bf(qkv_w[o * C_ + c] * inv);
    if (c == 0) biasq[o] = qb[o] * s - qm[o] * inv;
  } else {
    int oo = o - QKV_OUT_;
    float inv = pg[oo] * rsqrtf(pv[oo] + BN_EPS);
    wp[oo * C_ + c] = f2bf(proj_w[oo * C_ + c] * inv);
    if (c == 0) biasp[oo] = pb[oo] - pm[oo] * inv;
  }
}

// ---------------------------------------------------------------------------
// qkv GEMM: fused x transpose, tile 128(o) x 128(tok), BK=32, double-
// buffered LDS stride 44 shorts, reg-prefetch, 1 barrier per K-step.
// Round 5: staging f32->bf16 packing via v_cvt_pk_bf16_f32 (1 instr, HW RNE)
// instead of manual RNE bit-twiddle (8 x ~8 VALU per K-step -> 8 x 1).
// Epilogue: q,k -> token-major qkT[b][h][token][32]; v -> planar bf16 vbuf.
// ---------------------------------------------------------------------------
__global__ __launch_bounds__(256) void gemm_qkv(
    const float* __restrict__ x, const unsigned short* __restrict__ wq,
    const float* __restrict__ bias,
    unsigned short* __restrict__ qkT, unsigned short* __restrict__ vbuf)
{
  constexpr int STR = 44;
  __shared__ __align__(8) unsigned short wa[2][128 * STR];
  __shared__ __align__(8) unsigned short xb[2][128 * STR];
  const int tid = threadIdx.x;
  const int wave = tid >> 6, lane = tid & 63, l31 = lane & 31, lh = lane >> 5;
  const int wm = wave & 1, wn = wave >> 1;
  const int b = blockIdx.x >> 3, nloc = (blockIdx.x & 7) * 128;
  const int o0 = blockIdx.y * 128;

  // A staging: 512 slots of 16B; thread covers slots tid, tid+256
  const int r0 = tid >> 2, oc0 = (tid & 3) * 8;
  const int r1 = r0 + 64;
  // B staging: token tok, channel half chalf (16 ch), 16 scalar f32 loads
  const int tok = tid & 127, chalf = (tid >> 7) * 16;
  const float* xbase = x + (size_t)b * C_ * N_ + nloc + tok;

  uint4 ga0, ga1;
  float nb[16];

  auto loadk = [&](int kc) {
    ga0 = *(const uint4*)(wq + (size_t)(o0 + r0) * C_ + kc * 32 + oc0);
    ga1 = *(const uint4*)(wq + (size_t)(o0 + r1) * C_ + kc * 32 + oc0);
    #pragma unroll
    for (int j = 0; j < 16; ++j)
      nb[j] = xbase[(size_t)(kc * 32 + chalf + j) * N_];
  };
  auto storek = [&](int bufi) {
    lds_store16(&wa[bufi][r0 * STR + oc0], ga0);
    lds_store16(&wa[bufi][r1 * STR + oc0], ga1);
    unsigned int pk[8];
    #pragma unroll
    for (int q = 0; q < 8; ++q) pk[q] = cvt_pk_bf16(nb[2 * q], nb[2 * q + 1]);
    lds_store16(&xb[bufi][tok * STR + chalf], make_uint4(pk[0], pk[1], pk[2], pk[3]));
    lds_store16(&xb[bufi][tok * STR + chalf + 8], make_uint4(pk[4], pk[5], pk[6], pk[7]));
  };

  float16 acc[2][2];
  #pragma unroll
  for (int i = 0; i < 2; ++i)
    #pragma unroll
    for (int j = 0; j < 2; ++j) acc[i][j] = zero16();

  loadk(0);
  storek(0);
  __syncthreads();

  for (int kc = 0; kc < 8; ++kc) {
    const int buf = kc & 1;
    if (kc < 7) loadk(kc + 1);   // global loads land during MFMA

    #pragma unroll
    for (int ks = 0; ks < 2; ++ks) {
      const int ko = ks * 16 + lh * 8;
      short8 a0 = lds_frag(&wa[buf][(wm * 64 + l31) * STR + ko]);
      short8 a1 = lds_frag(&wa[buf][(wm * 64 + 32 + l31) * STR + ko]);
      short8 b0 = lds_frag(&xb[buf][(wn * 64 + l31) * STR + ko]);
      short8 b1 = lds_frag(&xb[buf][(wn * 64 + 32 + l31) * STR + ko]);
      acc[0][0] = __builtin_amdgcn_mfma_f32_32x32x16_bf16(a0, b0, acc[0][0], 0, 0, 0);
      acc[0][1] = __builtin_amdgcn_mfma_f32_32x32x16_bf16(a0, b1, acc[0][1], 0, 0, 0);
      acc[1][0] = __builtin_amdgcn_mfma_f32_32x32x16_bf16(a1, b0, acc[1][0], 0, 0, 0);
      acc[1][1] = __builtin_amdgcn_mfma_f32_32x32x16_bf16(a1, b1, acc[1][1], 0, 0, 0);
    }

    if (kc < 7) storek(buf ^ 1);
    __syncthreads();
  }

  const int hh = (o0 >> 6) + wm;  // o = o0 + wm*64 + am*32 + idx
  // am=0: q+k -> token-major qkT[b][hh][token][cc]
  #pragma unroll
  for (int bn = 0; bn < 2; ++bn) {
    int n = nloc + wn * 64 + bn * 32 + l31;
    unsigned short* row = qkT + (((size_t)b * NH + hh) * N_ + n) * 32;
    #pragma unroll
    for (int qd = 0; qd < 4; ++qd) {
      int cc0 = 8 * qd + 4 * lh;
      ushort4 rv;
      rv.x = f2bf(acc[0][bn][4 * qd + 0] + bias[hh * 64 + cc0 + 0]);
      rv.y = f2bf(acc[0][bn][4 * qd + 1] + bias[hh * 64 + cc0 + 1]);
      rv.z = f2bf(acc[0][bn][4 * qd + 2] + bias[hh * 64 + cc0 + 2]);
      rv.w = f2bf(acc[0][bn][4 * qd + 3] + bias[hh * 64 + cc0 + 3]);
      *(ushort4*)(row + cc0) = rv;
    }
  }
  // am=1: v -> planar bf16 vbuf[b][hh*32+d][n]
  #pragma unroll
  for (int r = 0; r < 16; ++r) {
    int d = (r & 3) + 8 * (r >> 2) + 4 * lh;
    float bo = bias[hh * 64 + 32 + d];
    unsigned short* vrow =
        vbuf + ((size_t)b * C_ + hh * 32 + d) * N_ + nloc + wn * 64 + l31;
    #pragma unroll
    for (int bn = 0; bn < 2; ++bn)
      vrow[bn * 32] = f2bf(acc[1][bn][r] + bo);
  }
}

// ---------------------------------------------------------------------------
// proj GEMM: 64(o) x 128(tok) tile, grid (128,4) = 512 blocks = 2/CU,
// LDS 34 KB.  Double-buffered stride-44 pipeline, 1 barrier per K-step.
// f32 planar out.
// ---------------------------------------------------------------------------
__global__ __launch_bounds__(256) void gemm_proj(
    const unsigned short* __restrict__ inT, const unsigned short* __restrict__ wp,
    const float* __restrict__ bias, float* __restrict__ outf)
{
  constexpr int STR = 44;
  __shared__ __align__(8) unsigned short wa[2][64 * STR];
  __shared__ __align__(8) unsigned short xb[2][128 * STR];
  const int tid = threadIdx.x;
  const int wave = tid >> 6, lane = tid & 63, l31 = lane & 31, lh = lane >> 5;
  const int wm = wave & 1, wn = wave >> 1;
  const int n0g = blockIdx.x * 128;
  const int o0 = blockIdx.y * 64;
  const int b = n0g >> 10, nloc = n0g & 1023;

  // A staging: 64 rows x 32 ch = 256 16B-slots (1/thread)
  const int ar = tid >> 2, aseg = (tid & 3) * 8;
  // B staging: 128 rows x 32 ch = 512 slots (2/thread: rows ar, ar+64)

  float16 acc[2];
  acc[0] = zero16(); acc[1] = zero16();

  uint4 ga, gb0, gb1;
  auto loadk = [&](int kc) {
    ga  = *(const uint4*)(wp + (size_t)(o0 + ar) * C_ + kc * 32 + aseg);
    gb0 = *(const uint4*)(inT + (size_t)(n0g + ar) * C_ + kc * 32 + aseg);
    gb1 = *(const uint4*)(inT + (size_t)(n0g + ar + 64) * C_ + kc * 32 + aseg);
  };
  auto storek = [&](int bufi) {
    lds_store16(&wa[bufi][ar * STR + aseg], ga);
    lds_store16(&xb[bufi][ar * STR + aseg], gb0);
    lds_store16(&xb[bufi][(ar + 64) * STR + aseg], gb1);
  };

  loadk(0);
  storek(0);
  __syncthreads();

  for (int kc = 0; kc < 8; ++kc) {
    const int buf = kc & 1;
    if (kc < 7) loadk(kc + 1);

    #pragma unroll
    for (int ks = 0; ks < 2; ++ks) {
      const int ko = ks * 16 + lh * 8;
      short8 a0 = lds_frag(&wa[buf][(wm * 32 + l31) * STR + ko]);
      short8 b0 = lds_frag(&xb[buf][(wn * 64 + l31) * STR + ko]);
      short8 b1 = lds_frag(&xb[buf][(wn * 64 + 32 + l31) * STR + ko]);
      acc[0] = __builtin_amdgcn_mfma_f32_32x32x16_bf16(a0, b0, acc[0], 0, 0, 0);
      acc[1] = __builtin_amdgcn_mfma_f32_32x32x16_bf16(a0, b1, acc[1], 0, 0, 0);
    }

    if (kc < 7) storek(buf ^ 1);
    __syncthreads();
  }

  #pragma unroll
  for (int r = 0; r < 16; ++r) {
    int o = o0 + wm * 32 + (r & 3) + 8 * (r >> 2) + 4 * lh;
    float bo = bias[o];
    float* orow = outf + ((size_t)b * C_ + o) * N_ + nloc + wn * 64 + l31;
    #pragma unroll
    for (int bn = 0; bn < 2; ++bn)
      orow[bn * 32] = acc[bn][r] + bo;
  }
}

// ---------------------------------------------------------------------------
// MFMA attention (round-4 version, UNCHANGED): 64 q/wave (two 32-row groups
// per wave) for 2x ILP on the latency-bound QK->exp->PV chain; kf/vf LDS
// reads shared between groups; s_setprio(1) around MFMA clusters; 512
// blocks; posenc fused as cooperative LDS pass over 8 image rows.
// ---------------------------------------------------------------------------
__global__ __launch_bounds__(256, 2) void attn_mfma(
    const unsigned short* __restrict__ qkT, const unsigned short* __restrict__ vbuf,
    const float* __restrict__ pw, const float* __restrict__ peg,
    const float* __restrict__ peb, const float* __restrict__ pem,
    const float* __restrict__ pev, unsigned short* __restrict__ vattnT)
{
  // flat pool: main loop uses kl[2][128*28] (7168) + vl[2][32*140] (8960).
  // posenc phase reuses it: w12 [32][12] f32 (768 sh) | guard 8 sh |
  // ptb [32][10][40] (12800 sh) | pout [32][8][32] (8192 sh) = 21776 sh.
  __shared__ __align__(16) unsigned short smem[21792];
  unsigned short* kl = smem;            // [2][3584]
  unsigned short* vl = smem + 7168;     // [2][4480]

  const int tid = threadIdx.x;
  const int wave = tid >> 6, lane = tid & 63;
  const int l31 = lane & 31, lh = lane >> 5;
  const int b = blockIdx.x >> 3, h = blockIdx.x & 7;
  const int qbase = blockIdx.y * 256 + wave * 64;

  const unsigned short* qkb = qkT + ((size_t)b * NH + h) * N_ * 32;
  const unsigned short* vhead = vbuf + ((size_t)b * C_ + h * HD) * N_;

  const int skey = tid >> 1, shalf = tid & 1;
  const int svd = tid >> 3, svseg = tid & 7;

  // Q fragments for both 32-row groups (scale pre-folded in weights)
  short8 qfE = *(const short8*)(qkb + (size_t)(qbase + l31) * 32 + lh * 8);
  short8 qfF = *(const short8*)(qkb + (size_t)(qbase + 32 + l31) * 32 + lh * 8);

  uint4 gk, gv0, gv1;
  auto loadc = [&](int kc) {
    gk  = *(const uint4*)(qkb + (size_t)(kc + skey) * 32 + 16 + shalf * 8);
    gv0 = *(const uint4*)(vhead + (size_t)svd * N_ + kc + svseg * 16);
    gv1 = *(const uint4*)(vhead + (size_t)svd * N_ + kc + svseg * 16 + 8);
  };
  auto storec = [&](int bufi) {
    lds_store16(&kl[bufi * 3584 + skey * 28 + shalf * 8], gk);
    lds_store16(&vl[bufi * 4480 + svd * 140 + svseg * 16], gv0);
    lds_store16(&vl[bufi * 4480 + svd * 140 + svseg * 16 + 8], gv1);
  };

  loadc(0);
  storec(0);
  __syncthreads();

  float16 o0E = zero16(), o0O = zero16(), o1E = zero16(), o1O = zero16();
  float lsE[4] = {0.f, 0.f, 0.f, 0.f};
  float lsF[4] = {0.f, 0.f, 0.f, 0.f};

  for (int c = 0; c < 8; ++c) {
    const int buf = c & 1;
    if (c < 7) loadc((c + 1) * 128);

    #pragma unroll
    for (int t = 0; t < 4; ++t) {
      const int key0 = t * 32;
      // shared operands: one K fragment + both V fragments, hoisted so LDS
      // latency overlaps the MFMA/exp work
      short8 kf  = lds_frag(&kl[buf * 3584 + (key0 + l31) * 28 + lh * 8]);
      short8 vf0 = lds_frag(&vl[buf * 4480 + l31 * 140 + key0 + lh * 8]);
      short8 vf1 = lds_frag(&vl[buf * 4480 + l31 * 140 + key0 + 16 + lh * 8]);

      __builtin_amdgcn_s_setprio(1);
      float16 stE = __builtin_amdgcn_mfma_f32_32x32x16_bf16(kf, qfE, zero16(), 0, 0, 0);
      float16 stF = __builtin_amdgcn_mfma_f32_32x32x16_bf16(kf, qfF, zero16(), 0, 0, 0);
      __builtin_amdgcn_s_setprio(0);

      unsigned int uE[8], uF[8];
      #pragma unroll
      for (int q = 0; q < 8; ++q) {
        float pe = fast_exp2(stE[2 * q]);
        float po = fast_exp2(stE[2 * q + 1]);
        lsE[q & 3] += pe + po;
        uE[q] = pack_bf16_trunc(pe, po);
      }
      #pragma unroll
      for (int q = 0; q < 8; ++q) {
        float pe = fast_exp2(stF[2 * q]);
        float po = fast_exp2(stF[2 * q + 1]);
        lsF[q & 3] += pe + po;
        uF[q] = pack_bf16_trunc(pe, po);
      }

      union { unsigned int w[4]; short8 s; } bE0, bE1, bF0, bF1;
      {
        unsigned int a0 = uE[0], a2 = uE[2]; pl32(a0, a2);
        unsigned int a1 = uE[1], a3 = uE[3]; pl32(a1, a3);
        bE0.w[0] = a0; bE0.w[1] = a1; bE0.w[2] = a2; bE0.w[3] = a3;
        unsigned int c0 = uE[4], c2 = uE[6]; pl32(c0, c2);
        unsigned int c1 = uE[5], c3 = uE[7]; pl32(c1, c3);
        bE1.w[0] = c0; bE1.w[1] = c1; bE1.w[2] = c2; bE1.w[3] = c3;
      }
      {
        unsigned int a0 = uF[0], a2 = uF[2]; pl32(a0, a2);
        unsigned int a1 = uF[1], a3 = uF[3]; pl32(a1, a3);
        bF0.w[0] = a0; bF0.w[1] = a1; bF0.w[2] = a2; bF0.w[3] = a3;
        unsigned int c0 = uF[4], c2 = uF[6]; pl32(c0, c2);
        unsigned int c1 = uF[5], c3 = uF[7]; pl32(c1, c3);
        bF1.w[0] = c0; bF1.w[1] = c1; bF1.w[2] = c2; bF1.w[3] = c3;
      }

      __builtin_amdgcn_s_setprio(1);
      o0E = __builtin_amdgcn_mfma_f32_32x32x16_bf16(vf0, bE0.s, o0E, 0, 0, 0);
      o1E = __builtin_amdgcn_mfma_f32_32x32x16_bf16(vf0, bF0.s, o1E, 0, 0, 0);
      o0O = __builtin_amdgcn_mfma_f32_32x32x16_bf16(vf1, bE1.s, o0O, 0, 0, 0);
      o1O = __builtin_amdgcn_mfma_f32_32x32x16_bf16(vf1, bF1.s, o1O, 0, 0, 0);
      __builtin_amdgcn_s_setprio(0);
    }

    if (c < 7) storec(buf ^ 1);
    __syncthreads();
  }
  // loop-end barrier passed: all waves done with K/V LDS -> reuse pool.

  // ---- posenc stage A: 10-row v tile + BN-folded weights into LDS -------
  const int R0 = blockIdx.y * 8;
  float* w12 = (float*)smem;                 // [32][12] f32
  unsigned short* ptb = smem + 776;          // guard at [768..775]
  unsigned short* pout = smem + 13576;       // [32][8][32]

  if (tid == 0) lds_store16(&smem[768], make_uint4(0, 0, 0, 0));  // guard
  #pragma unroll
  for (int it = 0; it < 2; ++it) {
    const int i = tid + it * 256;
    if (i < 320) {
      const int d = i / 10, ry = i - d * 10;
      unsigned short* dst = ptb + d * 400 + ry * 40;
      const uint4 z = make_uint4(0, 0, 0, 0);
      lds_store16(dst + 32, z);                                // right pad
      const int yy = R0 - 1 + ry;
      if (yy >= 0 && yy < 32) {
        const unsigned short* src = vhead + (size_t)d * N_ + yy * 32;
        lds_store16(dst,      *(const uint4*)(src));
        lds_store16(dst + 8,  *(const uint4*)(src + 8));
        lds_store16(dst + 16, *(const uint4*)(src + 16));
        lds_store16(dst + 24, *(const uint4*)(src + 24));
      } else {
        lds_store16(dst, z); lds_store16(dst + 8, z);
        lds_store16(dst + 16, z); lds_store16(dst + 24, z);
      }
    }
  }
  if (tid < 32) {
    const int cg = h * HD + tid;
    const float iv = peg[cg] * rsqrtf(pev[cg] + BN_EPS);
    float* wr = w12 + tid * 12;
    #pragma unroll
    for (int k = 0; k < 9; ++k) wr[k] = pw[cg * 9 + k] * iv;
    wr[9] = peb[cg] - pem[cg] * iv;
    wr[10] = 0.f; wr[11] = 0.f;
  }
  __syncthreads();

  // ---- posenc compute: 512 items = (d, row(8), 16-px strip), 2/thread ---
  #pragma unroll
  for (int it = 0; it < 2; ++it) {
    const int item = tid + it * 256;
    const int d = item >> 4, row = (item >> 1) & 7, x0 = (item & 1) * 16;
    const float* wr = w12 + d * 12;
    float wv[10];
    #pragma unroll
    for (int k = 0; k < 10; ++k) wv[k] = wr[k];
    float acc[16];
    #pragma unroll
    for (int j = 0; j < 16; ++j) acc[j] = wv[9];
    #pragma unroll
    for (int dy = 0; dy < 3; ++dy) {
      const unsigned short* base = ptb + d * 400 + (row + dy) * 40 + x0;
      float tv[18];
      tv[0] = bf2f(base[-1]);                      // pad/guard = 0
      short8 s0 = lds_frag(base);
      short8 s1 = lds_frag(base + 8);
      #pragma unroll
      for (int j = 0; j < 8; ++j) {
        tv[1 + j] = bf2f((unsigned short)s0[j]);
        tv[9 + j] = bf2f((unsigned short)s1[j]);
      }
      tv[17] = bf2f(base[16]);                     // pad = 0 at x0=16
      const float w0 = wv[dy * 3], w1 = wv[dy * 3 + 1], w2 = wv[dy * 3 + 2];
      #pragma unroll
      for (int j = 0; j < 16; ++j)
        acc[j] += w0 * tv[j] + w1 * tv[j + 1] + w2 * tv[j + 2];
    }
    unsigned short* po = pout + d * 256 + row * 32 + x0;
    unsigned int pk[8];
    #pragma unroll
    for (int q = 0; q < 8; ++q) pk[q] = pack_bf16_rne(acc[2 * q], acc[2 * q + 1]);
    lds_store16(po,     make_uint4(pk[0], pk[1], pk[2], pk[3]));
    lds_store16(po + 8, make_uint4(pk[4], pk[5], pk[6], pk[7]));
  }
  __syncthreads();

  // ---- softmax finish + gather posenc + token-major store (2 groups) ----
  float lsumE = (lsE[0] + lsE[1]) + (lsE[2] + lsE[3]);
  lsumE += __shfl_xor(lsumE, 32, 64);
  const float linvE = 1.f / lsumE;
  float lsumF = (lsF[0] + lsF[1]) + (lsF[2] + lsF[3]);
  lsumF += __shfl_xor(lsumF, 32, 64);
  const float linvF = 1.f / lsumF;

  auto emit = [&](const float16& aE, const float16& aO, float linv, int g) {
    const int token = qbase + g * 32 + l31;
    const int yl = wave * 2 + g;                 // local image row in pout
    float val[16];
    #pragma unroll
    for (int r = 0; r < 16; ++r) {
      int d = (r & 3) + 8 * (r >> 2) + 4 * lh;
      val[r] = (aE[r] + aO[r]) * linv + bf2f(pout[d * 256 + yl * 32 + l31]);
    }
    unsigned int u[8];
    #pragma unroll
    for (int m = 0; m < 8; ++m) u[m] = pack_bf16_rne(val[2 * m], val[2 * m + 1]);
    pl32(u[0], u[4]); pl32(u[1], u[5]); pl32(u[2], u[6]); pl32(u[3], u[7]);
    unsigned short* row = vattnT + ((size_t)b * N_ + token) * C_ + h * HD + lh * 16;
    *(uint4*)(row)     = make_uint4(u[0], u[1], u[4], u[5]);
    *(uint4*)(row + 8) = make_uint4(u[2], u[3], u[6], u[7]);
  };
  emit(o0E, o0O, linvE, 0);
  emit(o1E, o1O, linvF, 1);
}

// ---------------------------------------------------------------------------
extern "C" void kernel_launch(void* const* d_in, const int* in_sizes, int n_in,
                              void* d_out, int out_size, void* d_ws, size_t ws_size,
                              hipStream_t stream) {
  const float* x          = (const float*)d_in[0];
  const float* qkv_w      = (const float*)d_in[1];
  const float* qkv_gamma  = (const float*)d_in[2];
  const float* qkv_beta   = (const float*)d_in[3];
  const float* qkv_mean   = (const float*)d_in[4];
  const float* qkv_var    = (const float*)d_in[5];
  const float* pe_w       = (const float*)d_in[6];
  const float* pe_gamma   = (const float*)d_in[7];
  const float* pe_beta    = (const float*)d_in[8];
  const float* pe_mean    = (const float*)d_in[9];
  const float* pe_var     = (const float*)d_in[10];
  const float* proj_w     = (const float*)d_in[11];
  const float* proj_gamma = (const float*)d_in[12];
  const float* proj_beta  = (const float*)d_in[13];
  const float* proj_mean  = (const float*)d_in[14];
  const float* proj_var   = (const float*)d_in[15];
  float* out = (float*)d_out;

  char* ws = (char*)d_ws;
  unsigned short* qkT = (unsigned short*)ws;
  ws += (size_t)B_ * NH * N_ * 32 * sizeof(unsigned short);
  unsigned short* vbuf = (unsigned short*)ws;
  ws += (size_t)B_ * C_ * N_ * sizeof(unsigned short);
  unsigned short* vattnT = (unsigned short*)ws;
  ws += (size_t)B_ * N_ * C_ * sizeof(unsigned short);
  unsigned short* wq = (unsigned short*)ws;
  ws += (size_t)QKV_OUT_ * C_ * sizeof(unsigned short);
  unsigned short* wp = (unsigned short*)ws;
  ws += (size_t)C_ * C_ * sizeof(unsigned short);
  float* biasq = (float*)ws; ws += QKV_OUT_ * sizeof(float);
  float* biasp = (float*)ws;

  fold_weights<<<dim3(QKV_OUT_ + C_), 256, 0, stream>>>(
      qkv_w, qkv_gamma, qkv_beta, qkv_mean, qkv_var,
      proj_w, proj_gamma, proj_beta, proj_mean, proj_var,
      wq, biasq, wp, biasp);

  // qkv GEMM (fused transpose): grid.x = (b, ntile), grid.y = otile
  gemm_qkv<<<dim3(128, 4), 256, 0, stream>>>(x, wq, biasq, qkT, vbuf);

  // attention (64 q/wave, posenc fused): grid.x = bh, grid.y = q-tile(256)
  attn_mfma<<<dim3(128, 4), 256, 0, stream>>>(
      qkT, vbuf, pe_w, pe_gamma, pe_beta, pe_mean, pe_var, vattnT);

  // proj GEMM: grid (ntile, otile) = 512 blocks (2/CU)
  gemm_proj<<<dim3(128, 4), 256, 0, stream>>>(vattnT, wp, biasp, out);
}

// Round 6
// 145.771 us; speedup vs baseline: 1.0950x; 1.0038x over previous
//
#include <hip/hip_runtime.h>

#define B_ 16
#define C_ 256
#define N_ 1024
#define NH 8
#define HD 32
#define KD 16
#define QKV_OUT_ 512
#define BN_EPS 1e-3f
// softmax scale * log2(e), folded into the q-channel weight scaling
#define SCALE2_ (0.25f * 1.44269504088896f)

typedef __attribute__((ext_vector_type(8))) short short8;
typedef __attribute__((ext_vector_type(16))) float float16;

__device__ inline unsigned short f2bf(float f) {
  unsigned int u = __float_as_uint(f);
  return (unsigned short)((u + 0x7FFF + ((u >> 16) & 1)) >> 16);  // RNE
}
__device__ inline float bf2f(unsigned short s) {
  return __uint_as_float(((unsigned int)s) << 16);
}
__device__ inline float16 zero16() {
  float16 z;
  #pragma unroll
  for (int i = 0; i < 16; ++i) z[i] = 0.f;
  return z;
}
__device__ inline unsigned int pack_bf16_trunc(float a, float b) {
  return __builtin_amdgcn_perm(__float_as_uint(b), __float_as_uint(a), 0x07060302u);
}
__device__ inline unsigned int pack_bf16_rne(float a, float b) {
  return (unsigned int)f2bf(a) | ((unsigned int)f2bf(b) << 16);
}
// single-instruction packed f32x2 -> bf16x2 (RNE in HW; no builtin on gfx950)
__device__ inline unsigned int cvt_pk_bf16(float lo, float hi) {
  unsigned int d;
  asm("v_cvt_pk_bf16_f32 %0, %1, %2" : "=v"(d) : "v"(lo), "v"(hi));
  return d;
}
__device__ inline float fast_exp2(float x) {
#if __has_builtin(__builtin_amdgcn_exp2f)
  return __builtin_amdgcn_exp2f(x);
#else
  return exp2f(x);
#endif
}
// permlane32_swap: a' = {a.lo, b.lo}, b' = {a.hi, b.hi}
__device__ inline void pl32(unsigned int& a, unsigned int& b) {
#if __has_builtin(__builtin_amdgcn_permlane32_swap)
  typedef __attribute__((ext_vector_type(2))) int int2v;
  int2v r = __builtin_amdgcn_permlane32_swap((int)a, (int)b, false, false);
  a = (unsigned int)r[0];
  b = (unsigned int)r[1];
#else
  unsigned int ea = (unsigned int)__shfl_xor((int)a, 32, 64);
  unsigned int eb = (unsigned int)__shfl_xor((int)b, 32, 64);
  bool hi = (threadIdx.x & 32) != 0;
  unsigned int an = hi ? eb : a;
  unsigned int bn = hi ? b : ea;
  a = an; b = bn;
#endif
}
__device__ inline short8 lds_frag(const unsigned short* p) {
  union { uint2 u[2]; short8 s; } r;
  r.u[0] = *(const uint2*)p;
  r.u[1] = *(const uint2*)(p + 4);
  return r.s;
}
__device__ inline void lds_store16(unsigned short* p, uint4 v) {
  *(uint2*)p = make_uint2(v.x, v.y);
  *(uint2*)(p + 4) = make_uint2(v.z, v.w);
}

// ---------------------------------------------------------------------------
// qkv GEMM, round 6: BN weight-fold moved INTO staging (fold_weights kernel
// eliminated).  A-staging reads raw f32 qkv_w, scales by per-row inv[o]
// (computed once per thread at entry; q-channels include SCALE2_) and packs
// with v_cvt_pk_bf16_f32 -- r5 proved staging VALU is off the critical path.
// Biases computed cooperatively into LDS at block start.  Arithmetic is
// bit-identical to the old fold path.  Fused x transpose B-staging, tile
// 128x128, BK=32, double-buffered stride-44 LDS, 1 barrier per K-step.
// Epilogue: q,k -> token-major qkT[b][h][token][32]; v -> planar bf16 vbuf.
// ---------------------------------------------------------------------------
__global__ __launch_bounds__(256) void gemm_qkv(
    const float* __restrict__ x, const float* __restrict__ qkv_w,
    const float* __restrict__ qg, const float* __restrict__ qb,
    const float* __restrict__ qm, const float* __restrict__ qv,
    unsigned short* __restrict__ qkT, unsigned short* __restrict__ vbuf)
{
  constexpr int STR = 44;
  __shared__ __align__(8) unsigned short wa[2][128 * STR];
  __shared__ __align__(8) unsigned short xb[2][128 * STR];
  __shared__ float biasl[128];
  const int tid = threadIdx.x;
  const int wave = tid >> 6, lane = tid & 63, l31 = lane & 31, lh = lane >> 5;
  const int wm = wave & 1, wn = wave >> 1;
  const int b = blockIdx.x >> 3, nloc = (blockIdx.x & 7) * 128;
  const int o0 = blockIdx.y * 128;

  // A staging: thread covers weight rows r0, r0+64; 8 f32 each per K-step
  const int r0 = tid >> 2, oc0 = (tid & 3) * 8;
  const int orow0 = o0 + r0, orow1 = orow0 + 64;
  const float sc0 = ((orow0 & 63) < 16) ? SCALE2_ : 1.f;
  const float sc1 = ((orow1 & 63) < 16) ? SCALE2_ : 1.f;
  const float inv0 = qg[orow0] * rsqrtf(qv[orow0] + BN_EPS) * sc0;
  const float inv1 = qg[orow1] * rsqrtf(qv[orow1] + BN_EPS) * sc1;
  if (tid < 128) {
    const int o = o0 + tid;
    const float ss = ((o & 63) < 16) ? SCALE2_ : 1.f;
    const float iv = qg[o] * rsqrtf(qv[o] + BN_EPS) * ss;
    biasl[tid] = qb[o] * ss - qm[o] * iv;
  }

  // B staging: token tok, channel half chalf (16 ch), 16 scalar f32 loads
  const int tok = tid & 127, chalf = (tid >> 7) * 16;
  const float* xbase = x + (size_t)b * C_ * N_ + nloc + tok;

  float aw0[8], aw1[8];
  float nb[16];

  auto loadk = [&](int kc) {
    const float* a0p = qkv_w + (size_t)orow0 * C_ + kc * 32 + oc0;
    const float* a1p = qkv_w + (size_t)orow1 * C_ + kc * 32 + oc0;
    *(float4*)(aw0)     = *(const float4*)(a0p);
    *(float4*)(aw0 + 4) = *(const float4*)(a0p + 4);
    *(float4*)(aw1)     = *(const float4*)(a1p);
    *(float4*)(aw1 + 4) = *(const float4*)(a1p + 4);
    #pragma unroll
    for (int j = 0; j < 16; ++j)
      nb[j] = xbase[(size_t)(kc * 32 + chalf + j) * N_];
  };
  auto storek = [&](int bufi) {
    unsigned int pa[4];
    #pragma unroll
    for (int q = 0; q < 4; ++q)
      pa[q] = cvt_pk_bf16(aw0[2 * q] * inv0, aw0[2 * q + 1] * inv0);
    lds_store16(&wa[bufi][r0 * STR + oc0], make_uint4(pa[0], pa[1], pa[2], pa[3]));
    #pragma unroll
    for (int q = 0; q < 4; ++q)
      pa[q] = cvt_pk_bf16(aw1[2 * q] * inv1, aw1[2 * q + 1] * inv1);
    lds_store16(&wa[bufi][(r0 + 64) * STR + oc0], make_uint4(pa[0], pa[1], pa[2], pa[3]));
    unsigned int pk[8];
    #pragma unroll
    for (int q = 0; q < 8; ++q) pk[q] = cvt_pk_bf16(nb[2 * q], nb[2 * q + 1]);
    lds_store16(&xb[bufi][tok * STR + chalf], make_uint4(pk[0], pk[1], pk[2], pk[3]));
    lds_store16(&xb[bufi][tok * STR + chalf + 8], make_uint4(pk[4], pk[5], pk[6], pk[7]));
  };

  float16 acc[2][2];
  #pragma unroll
  for (int i = 0; i < 2; ++i)
    #pragma unroll
    for (int j = 0; j < 2; ++j) acc[i][j] = zero16();

  loadk(0);
  storek(0);
  __syncthreads();

  for (int kc = 0; kc < 8; ++kc) {
    const int buf = kc & 1;
    if (kc < 7) loadk(kc + 1);   // global loads land during MFMA

    #pragma unroll
    for (int ks = 0; ks < 2; ++ks) {
      const int ko = ks * 16 + lh * 8;
      short8 a0 = lds_frag(&wa[buf][(wm * 64 + l31) * STR + ko]);
      short8 a1 = lds_frag(&wa[buf][(wm * 64 + 32 + l31) * STR + ko]);
      short8 b0 = lds_frag(&xb[buf][(wn * 64 + l31) * STR + ko]);
      short8 b1 = lds_frag(&xb[buf][(wn * 64 + 32 + l31) * STR + ko]);
      acc[0][0] = __builtin_amdgcn_mfma_f32_32x32x16_bf16(a0, b0, acc[0][0], 0, 0, 0);
      acc[0][1] = __builtin_amdgcn_mfma_f32_32x32x16_bf16(a0, b1, acc[0][1], 0, 0, 0);
      acc[1][0] = __builtin_amdgcn_mfma_f32_32x32x16_bf16(a1, b0, acc[1][0], 0, 0, 0);
      acc[1][1] = __builtin_amdgcn_mfma_f32_32x32x16_bf16(a1, b1, acc[1][1], 0, 0, 0);
    }

    if (kc < 7) storek(buf ^ 1);
    __syncthreads();
  }

  const int hh = (o0 >> 6) + wm;  // o = o0 + wm*64 + am*32 + idx
  // am=0: q+k -> token-major qkT[b][hh][token][cc]
  #pragma unroll
  for (int bn = 0; bn < 2; ++bn) {
    int n = nloc + wn * 64 + bn * 32 + l31;
    unsigned short* row = qkT + (((size_t)b * NH + hh) * N_ + n) * 32;
    #pragma unroll
    for (int qd = 0; qd < 4; ++qd) {
      int cc0 = 8 * qd + 4 * lh;
      ushort4 rv;
      rv.x = f2bf(acc[0][bn][4 * qd + 0] + biasl[wm * 64 + cc0 + 0]);
      rv.y = f2bf(acc[0][bn][4 * qd + 1] + biasl[wm * 64 + cc0 + 1]);
      rv.z = f2bf(acc[0][bn][4 * qd + 2] + biasl[wm * 64 + cc0 + 2]);
      rv.w = f2bf(acc[0][bn][4 * qd + 3] + biasl[wm * 64 + cc0 + 3]);
      *(ushort4*)(row + cc0) = rv;
    }
  }
  // am=1: v -> planar bf16 vbuf[b][hh*32+d][n]
  #pragma unroll
  for (int r = 0; r < 16; ++r) {
    int d = (r & 3) + 8 * (r >> 2) + 4 * lh;
    float bo = biasl[wm * 64 + 32 + d];
    unsigned short* vrow =
        vbuf + ((size_t)b * C_ + hh * 32 + d) * N_ + nloc + wn * 64 + l31;
    #pragma unroll
    for (int bn = 0; bn < 2; ++bn)
      vrow[bn * 32] = f2bf(acc[1][bn][r] + bo);
  }
}

// ---------------------------------------------------------------------------
// proj GEMM, round 6: BN fold moved into staging (raw f32 proj_w, per-row
// inv scale + cvt_pk during LDS store; bias in LDS).  64(o) x 128(tok)
// tile, grid (128,4) = 512 blocks, double-buffered stride-44 pipeline,
// 1 barrier per K-step.  f32 planar out.
// ---------------------------------------------------------------------------
__global__ __launch_bounds__(256) void gemm_proj(
    const unsigned short* __restrict__ inT, const float* __restrict__ proj_w,
    const float* __restrict__ pg, const float* __restrict__ pb,
    const float* __restrict__ pm, const float* __restrict__ pv,
    float* __restrict__ outf)
{
  constexpr int STR = 44;
  __shared__ __align__(8) unsigned short wa[2][64 * STR];
  __shared__ __align__(8) unsigned short xb[2][128 * STR];
  __shared__ float biasl[64];
  const int tid = threadIdx.x;
  const int wave = tid >> 6, lane = tid & 63, l31 = lane & 31, lh = lane >> 5;
  const int wm = wave & 1, wn = wave >> 1;
  const int n0g = blockIdx.x * 128;
  const int o0 = blockIdx.y * 64;
  const int b = n0g >> 10, nloc = n0g & 1023;

  // A staging: 64 rows x 32 ch; thread owns row ar (8 f32 per K-step)
  const int ar = tid >> 2, aseg = (tid & 3) * 8;
  const int orow = o0 + ar;
  const float inva = pg[orow] * rsqrtf(pv[orow] + BN_EPS);
  if (tid < 64) {
    const int o = o0 + tid;
    const float iv = pg[o] * rsqrtf(pv[o] + BN_EPS);
    biasl[tid] = pb[o] - pm[o] * iv;
  }

  float16 acc[2];
  acc[0] = zero16(); acc[1] = zero16();

  float awp[8];
  uint4 gb0, gb1;
  auto loadk = [&](int kc) {
    const float* ap = proj_w + (size_t)orow * C_ + kc * 32 + aseg;
    *(float4*)(awp)     = *(const float4*)(ap);
    *(float4*)(awp + 4) = *(const float4*)(ap + 4);
    gb0 = *(const uint4*)(inT + (size_t)(n0g + ar) * C_ + kc * 32 + aseg);
    gb1 = *(const uint4*)(inT + (size_t)(n0g + ar + 64) * C_ + kc * 32 + aseg);
  };
  auto storek = [&](int bufi) {
    unsigned int pa[4];
    #pragma unroll
    for (int q = 0; q < 4; ++q)
      pa[q] = cvt_pk_bf16(awp[2 * q] * inva, awp[2 * q + 1] * inva);
    lds_store16(&wa[bufi][ar * STR + aseg], make_uint4(pa[0], pa[1], pa[2], pa[3]));
    lds_store16(&xb[bufi][ar * STR + aseg], gb0);
    lds_store16(&xb[bufi][(ar + 64) * STR + aseg], gb1);
  };

  loadk(0);
  storek(0);
  __syncthreads();

  for (int kc = 0; kc < 8; ++kc) {
    const int buf = kc & 1;
    if (kc < 7) loadk(kc + 1);

    #pragma unroll
    for (int ks = 0; ks < 2; ++ks) {
      const int ko = ks * 16 + lh * 8;
      short8 a0 = lds_frag(&wa[buf][(wm * 32 + l31) * STR + ko]);
      short8 b0 = lds_frag(&xb[buf][(wn * 64 + l31) * STR + ko]);
      short8 b1 = lds_frag(&xb[buf][(wn * 64 + 32 + l31) * STR + ko]);
      acc[0] = __builtin_amdgcn_mfma_f32_32x32x16_bf16(a0, b0, acc[0], 0, 0, 0);
      acc[1] = __builtin_amdgcn_mfma_f32_32x32x16_bf16(a0, b1, acc[1], 0, 0, 0);
    }

    if (kc < 7) storek(buf ^ 1);
    __syncthreads();
  }

  #pragma unroll
  for (int r = 0; r < 16; ++r) {
    int ol = wm * 32 + (r & 3) + 8 * (r >> 2) + 4 * lh;
    float bo = biasl[ol];
    float* orow_p = outf + ((size_t)b * C_ + o0 + ol) * N_ + nloc + wn * 64 + l31;
    #pragma unroll
    for (int bn = 0; bn < 2; ++bn)
      orow_p[bn * 32] = acc[bn][r] + bo;
  }
}

// ---------------------------------------------------------------------------
// MFMA attention (round-4 version, UNCHANGED): 64 q/wave (two 32-row groups
// per wave) for 2x ILP on the latency-bound QK->exp->PV chain; kf/vf LDS
// reads shared between groups; s_setprio(1) around MFMA clusters; 512
// blocks; posenc fused as cooperative LDS pass over 8 image rows.
// ---------------------------------------------------------------------------
__global__ __launch_bounds__(256, 2) void attn_mfma(
    const unsigned short* __restrict__ qkT, const unsigned short* __restrict__ vbuf,
    const float* __restrict__ pw, const float* __restrict__ peg,
    const float* __restrict__ peb, const float* __restrict__ pem,
    const float* __restrict__ pev, unsigned short* __restrict__ vattnT)
{
  // flat pool: main loop uses kl[2][128*28] (7168) + vl[2][32*140] (8960).
  // posenc phase reuses it: w12 [32][12] f32 (768 sh) | guard 8 sh |
  // ptb [32][10][40] (12800 sh) | pout [32][8][32] (8192 sh) = 21776 sh.
  __shared__ __align__(16) unsigned short smem[21792];
  unsigned short* kl = smem;            // [2][3584]
  unsigned short* vl = smem + 7168;     // [2][4480]

  const int tid = threadIdx.x;
  const int wave = tid >> 6, lane = tid & 63;
  const int l31 = lane & 31, lh = lane >> 5;
  const int b = blockIdx.x >> 3, h = blockIdx.x & 7;
  const int qbase = blockIdx.y * 256 + wave * 64;

  const unsigned short* qkb = qkT + ((size_t)b * NH + h) * N_ * 32;
  const unsigned short* vhead = vbuf + ((size_t)b * C_ + h * HD) * N_;

  const int skey = tid >> 1, shalf = tid & 1;
  const int svd = tid >> 3, svseg = tid & 7;

  // Q fragments for both 32-row groups (scale pre-folded in weights)
  short8 qfE = *(const short8*)(qkb + (size_t)(qbase + l31) * 32 + lh * 8);
  short8 qfF = *(const short8*)(qkb + (size_t)(qbase + 32 + l31) * 32 + lh * 8);

  uint4 gk, gv0, gv1;
  auto loadc = [&](int kc) {
    gk  = *(const uint4*)(qkb + (size_t)(kc + skey) * 32 + 16 + shalf * 8);
    gv0 = *(const uint4*)(vhead + (size_t)svd * N_ + kc + svseg * 16);
    gv1 = *(const uint4*)(vhead + (size_t)svd * N_ + kc + svseg * 16 + 8);
  };
  auto storec = [&](int bufi) {
    lds_store16(&kl[bufi * 3584 + skey * 28 + shalf * 8], gk);
    lds_store16(&vl[bufi * 4480 + svd * 140 + svseg * 16], gv0);
    lds_store16(&vl[bufi * 4480 + svd * 140 + svseg * 16 + 8], gv1);
  };

  loadc(0);
  storec(0);
  __syncthreads();

  float16 o0E = zero16(), o0O = zero16(), o1E = zero16(), o1O = zero16();
  float lsE[4] = {0.f, 0.f, 0.f, 0.f};
  float lsF[4] = {0.f, 0.f, 0.f, 0.f};

  for (int c = 0; c < 8; ++c) {
    const int buf = c & 1;
    if (c < 7) loadc((c + 1) * 128);

    #pragma unroll
    for (int t = 0; t < 4; ++t) {
      const int key0 = t * 32;
      // shared operands: one K fragment + both V fragments, hoisted so LDS
      // latency overlaps the MFMA/exp work
      short8 kf  = lds_frag(&kl[buf * 3584 + (key0 + l31) * 28 + lh * 8]);
      short8 vf0 = lds_frag(&vl[buf * 4480 + l31 * 140 + key0 + lh * 8]);
      short8 vf1 = lds_frag(&vl[buf * 4480 + l31 * 140 + key0 + 16 + lh * 8]);

      __builtin_amdgcn_s_setprio(1);
      float16 stE = __builtin_amdgcn_mfma_f32_32x32x16_bf16(kf, qfE, zero16(), 0, 0, 0);
      float16 stF = __builtin_amdgcn_mfma_f32_32x32x16_bf16(kf, qfF, zero16(), 0, 0, 0);
      __builtin_amdgcn_s_setprio(0);

      unsigned int uE[8], uF[8];
      #pragma unroll
      for (int q = 0; q < 8; ++q) {
        float pe = fast_exp2(stE[2 * q]);
        float po = fast_exp2(stE[2 * q + 1]);
        lsE[q & 3] += pe + po;
        uE[q] = pack_bf16_trunc(pe, po);
      }
      #pragma unroll
      for (int q = 0; q < 8; ++q) {
        float pe = fast_exp2(stF[2 * q]);
        float po = fast_exp2(stF[2 * q + 1]);
        lsF[q & 3] += pe + po;
        uF[q] = pack_bf16_trunc(pe, po);
      }

      union { unsigned int w[4]; short8 s; } bE0, bE1, bF0, bF1;
      {
        unsigned int a0 = uE[0], a2 = uE[2]; pl32(a0, a2);
        unsigned int a1 = uE[1], a3 = uE[3]; pl32(a1, a3);
        bE0.w[0] = a0; bE0.w[1] = a1; bE0.w[2] = a2; bE0.w[3] = a3;
        unsigned int c0 = uE[4], c2 = uE[6]; pl32(c0, c2);
        unsigned int c1 = uE[5], c3 = uE[7]; pl32(c1, c3);
        bE1.w[0] = c0; bE1.w[1] = c1; bE1.w[2] = c2; bE1.w[3] = c3;
      }
      {
        unsigned int a0 = uF[0], a2 = uF[2]; pl32(a0, a2);
        unsigned int a1 = uF[1], a3 = uF[3]; pl32(a1, a3);
        bF0.w[0] = a0; bF0.w[1] = a1; bF0.w[2] = a2; bF0.w[3] = a3;
        unsigned int c0 = uF[4], c2 = uF[6]; pl32(c0, c2);
        unsigned int c1 = uF[5], c3 = uF[7]; pl32(c1, c3);
        bF1.w[0] = c0; bF1.w[1] = c1; bF1.w[2] = c2; bF1.w[3] = c3;
      }

      __builtin_amdgcn_s_setprio(1);
      o0E = __builtin_amdgcn_mfma_f32_32x32x16_bf16(vf0, bE0.s, o0E, 0, 0, 0);
      o1E = __builtin_amdgcn_mfma_f32_32x32x16_bf16(vf0, bF0.s, o1E, 0, 0, 0);
      o0O = __builtin_amdgcn_mfma_f32_32x32x16_bf16(vf1, bE1.s, o0O, 0, 0, 0);
      o1O = __builtin_amdgcn_mfma_f32_32x32x16_bf16(vf1, bF1.s, o1O, 0, 0, 0);
      __builtin_amdgcn_s_setprio(0);
    }

    if (c < 7) storec(buf ^ 1);
    __syncthreads();
  }
  // loop-end barrier passed: all waves done with K/V LDS -> reuse pool.

  // ---- posenc stage A: 10-row v tile + BN-folded weights into LDS -------
  const int R0 = blockIdx.y * 8;
  float* w12 = (float*)smem;                 // [32][12] f32
  unsigned short* ptb = smem + 776;          // guard at [768..775]
  unsigned short* pout = smem + 13576;       // [32][8][32]

  if (tid == 0) lds_store16(&smem[768], make_uint4(0, 0, 0, 0));  // guard
  #pragma unroll
  for (int it = 0; it < 2; ++it) {
    const int i = tid + it * 256;
    if (i < 320) {
      const int d = i / 10, ry = i - d * 10;
      unsigned short* dst = ptb + d * 400 + ry * 40;
      const uint4 z = make_uint4(0, 0, 0, 0);
      lds_store16(dst + 32, z);                                // right pad
      const int yy = R0 - 1 + ry;
      if (yy >= 0 && yy < 32) {
        const unsigned short* src = vhead + (size_t)d * N_ + yy * 32;
        lds_store16(dst,      *(const uint4*)(src));
        lds_store16(dst + 8,  *(const uint4*)(src + 8));
        lds_store16(dst + 16, *(const uint4*)(src + 16));
        lds_store16(dst + 24, *(const uint4*)(src + 24));
      } else {
        lds_store16(dst, z); lds_store16(dst + 8, z);
        lds_store16(dst + 16, z); lds_store16(dst + 24, z);
      }
    }
  }
  if (tid < 32) {
    const int cg = h * HD + tid;
    const float iv = peg[cg] * rsqrtf(pev[cg] + BN_EPS);
    float* wr = w12 + tid * 12;
    #pragma unroll
    for (int k = 0; k < 9; ++k) wr[k] = pw[cg * 9 + k] * iv;
    wr[9] = peb[cg] - pem[cg] * iv;
    wr[10] = 0.f; wr[11] = 0.f;
  }
  __syncthreads();

  // ---- posenc compute: 512 items = (d, row(8), 16-px strip), 2/thread ---
  #pragma unroll
  for (int it = 0; it < 2; ++it) {
    const int item = tid + it * 256;
    const int d = item >> 4, row = (item >> 1) & 7, x0 = (item & 1) * 16;
    const float* wr = w12 + d * 12;
    float wv[10];
    #pragma unroll
    for (int k = 0; k < 10; ++k) wv[k] = wr[k];
    float acc[16];
    #pragma unroll
    for (int j = 0; j < 16; ++j) acc[j] = wv[9];
    #pragma unroll
    for (int dy = 0; dy < 3; ++dy) {
      const unsigned short* base = ptb + d * 400 + (row + dy) * 40 + x0;
      float tv[18];
      tv[0] = bf2f(base[-1]);                      // pad/guard = 0
      short8 s0 = lds_frag(base);
      short8 s1 = lds_frag(base + 8);
      #pragma unroll
      for (int j = 0; j < 8; ++j) {
        tv[1 + j] = bf2f((unsigned short)s0[j]);
        tv[9 + j] = bf2f((unsigned short)s1[j]);
      }
      tv[17] = bf2f(base[16]);                     // pad = 0 at x0=16
      const float w0 = wv[dy * 3], w1 = wv[dy * 3 + 1], w2 = wv[dy * 3 + 2];
      #pragma unroll
      for (int j = 0; j < 16; ++j)
        acc[j] += w0 * tv[j] + w1 * tv[j + 1] + w2 * tv[j + 2];
    }
    unsigned short* po = pout + d * 256 + row * 32 + x0;
    unsigned int pk[8];
    #pragma unroll
    for (int q = 0; q < 8; ++q) pk[q] = pack_bf16_rne(acc[2 * q], acc[2 * q + 1]);
    lds_store16(po,     make_uint4(pk[0], pk[1], pk[2], pk[3]));
    lds_store16(po + 8, make_uint4(pk[4], pk[5], pk[6], pk[7]));
  }
  __syncthreads();

  // ---- softmax finish + gather posenc + token-major store (2 groups) ----
  float lsumE = (lsE[0] + lsE[1]) + (lsE[2] + lsE[3]);
  lsumE += __shfl_xor(lsumE, 32, 64);
  const float linvE = 1.f / lsumE;
  float lsumF = (lsF[0] + lsF[1]) + (lsF[2] + lsF[3]);
  lsumF += __shfl_xor(lsumF, 32, 64);
  const float linvF = 1.f / lsumF;

  auto emit = [&](const float16& aE, const float16& aO, float linv, int g) {
    const int token = qbase + g * 32 + l31;
    const int yl = wave * 2 + g;                 // local image row in pout
    float val[16];
    #pragma unroll
    for (int r = 0; r < 16; ++r) {
      int d = (r & 3) + 8 * (r >> 2) + 4 * lh;
      val[r] = (aE[r] + aO[r]) * linv + bf2f(pout[d * 256 + yl * 32 + l31]);
    }
    unsigned int u[8];
    #pragma unroll
    for (int m = 0; m < 8; ++m) u[m] = pack_bf16_rne(val[2 * m], val[2 * m + 1]);
    pl32(u[0], u[4]); pl32(u[1], u[5]); pl32(u[2], u[6]); pl32(u[3], u[7]);
    unsigned short* row = vattnT + ((size_t)b * N_ + token) * C_ + h * HD + lh * 16;
    *(uint4*)(row)     = make_uint4(u[0], u[1], u[4], u[5]);
    *(uint4*)(row + 8) = make_uint4(u[2], u[3], u[6], u[7]);
  };
  emit(o0E, o0O, linvE, 0);
  emit(o1E, o1O, linvF, 1);
}

// ---------------------------------------------------------------------------
extern "C" void kernel_launch(void* const* d_in, const int* in_sizes, int n_in,
                              void* d_out, int out_size, void* d_ws, size_t ws_size,
                              hipStream_t stream) {
  const float* x          = (const float*)d_in[0];
  const float* qkv_w      = (const float*)d_in[1];
  const float* qkv_gamma  = (const float*)d_in[2];
  const float* qkv_beta   = (const float*)d_in[3];
  const float* qkv_mean   = (const float*)d_in[4];
  const float* qkv_var    = (const float*)d_in[5];
  const float* pe_w       = (const float*)d_in[6];
  const float* pe_gamma   = (const float*)d_in[7];
  const float* pe_beta    = (const float*)d_in[8];
  const float* pe_mean    = (const float*)d_in[9];
  const float* pe_var     = (const float*)d_in[10];
  const float* proj_w     = (const float*)d_in[11];
  const float* proj_gamma = (const float*)d_in[12];
  const float* proj_beta  = (const float*)d_in[13];
  const float* proj_mean  = (const float*)d_in[14];
  const float* proj_var   = (const float*)d_in[15];
  float* out = (float*)d_out;

  char* ws = (char*)d_ws;
  unsigned short* qkT = (unsigned short*)ws;
  ws += (size_t)B_ * NH * N_ * 32 * sizeof(unsigned short);
  unsigned short* vbuf = (unsigned short*)ws;
  ws += (size_t)B_ * C_ * N_ * sizeof(unsigned short);
  unsigned short* vattnT = (unsigned short*)ws;

  // qkv GEMM (BN fold in staging): grid.x = (b, ntile), grid.y = otile
  gemm_qkv<<<dim3(128, 4), 256, 0, stream>>>(
      x, qkv_w, qkv_gamma, qkv_beta, qkv_mean, qkv_var, qkT, vbuf);

  // attention (64 q/wave, posenc fused): grid.x = bh, grid.y = q-tile(256)
  attn_mfma<<<dim3(128, 4), 256, 0, stream>>>(
      qkT, vbuf, pe_w, pe_gamma, pe_beta, pe_mean, pe_var, vattnT);

  // proj GEMM (BN fold in staging): grid (ntile, otile) = 512 blocks
  gemm_proj<<<dim3(128, 4), 256, 0, stream>>>(
      vattnT, proj_w, proj_gamma, proj_beta, proj_mean, proj_var, out);
}